// Round 1
// baseline (6203.236 us; speedup 1.0000x reference)
//
#include <hip/hip_runtime.h>
#include <math.h>

#define BB 512
#define TT 80
#define VV 80
#define DD 128
#define HH 256
#define FH 1024
#define EE 8
#define GG1 512
#define GG2 256
#define SLOTS 1280
#define MT 32
#define NTILES (SLOTS/MT)   // 40
#define KC 16

// ---------------- prep: transpose recurrent weights, bias sums ----------------
__global__ void prep_kernel(const float* __restrict__ Whh0, const float* __restrict__ Wih1,
                            const float* __restrict__ Whh1, const float* __restrict__ bih1,
                            const float* __restrict__ bhh1,
                            float* __restrict__ W0T, float* __restrict__ W1T,
                            float* __restrict__ bsum1)
{
    const long n1 = (long)EE * HH * FH;       // W0T [e][256][1024]
    const long n2 = (long)EE * 2 * HH * FH;   // W1T [e][512][1024]
    const long n3 = (long)EE * FH;            // bsum1
    const long ntot = n1 + n2 + n3;
    for (long idx = (long)blockIdx.x * blockDim.x + threadIdx.x; idx < ntot;
         idx += (long)gridDim.x * blockDim.x) {
        if (idx < n1) {
            long e = idx / ((long)HH * FH);
            long r = idx % ((long)HH * FH);
            long k = r / FH, gc = r % FH;
            W0T[idx] = Whh0[(e * FH + gc) * HH + k];
        } else if (idx < n1 + n2) {
            long i2 = idx - n1;
            long e = i2 / ((long)2 * HH * FH);
            long r = i2 % ((long)2 * HH * FH);
            long k = r / FH, gc = r % FH;
            W1T[i2] = (k < HH) ? Wih1[(e * FH + gc) * HH + k]
                               : Whh1[(e * FH + gc) * HH + (k - HH)];
        } else {
            long i3 = idx - n1 - n2;
            bsum1[i3] = bih1[i3] + bhh1[i3];
        }
    }
}

// ---------------- embW[e][tok][1024] = emb[e,tok] @ Wih0^T + bih0 + bhh0 ----------------
__global__ __launch_bounds__(256)
void embw_kernel(const float* __restrict__ emb, const float* __restrict__ Wih0,
                 const float* __restrict__ bih0, const float* __restrict__ bhh0,
                 float* __restrict__ embW)
{
    int e = blockIdx.x / VV, tok = blockIdx.x % VV;
    int tid = threadIdx.x;
    __shared__ float er[DD];
    if (tid < DD) er[tid] = emb[((size_t)e * VV + tok) * DD + tid];
    __syncthreads();
    for (int gc = tid; gc < FH; gc += 256) {
        float s = bih0[e * FH + gc] + bhh0[e * FH + gc];
        const float* wr = Wih0 + ((size_t)e * FH + gc) * DD;
        #pragma unroll 4
        for (int d = 0; d < DD; d++) s += er[d] * wr[d];
        embW[((size_t)e * VV + tok) * FH + gc] = s;
    }
}

// ---------------- gating: feat -> MLP -> softmax -> top2 ----------------
__global__ __launch_bounds__(128)
void gating_kernel(const int* __restrict__ x, const float* __restrict__ emb,
                   const float* __restrict__ gw1, const float* __restrict__ gb1,
                   const float* __restrict__ g1g, const float* __restrict__ g1b,
                   const float* __restrict__ g1m, const float* __restrict__ g1v,
                   const float* __restrict__ gw2, const float* __restrict__ gb2,
                   const float* __restrict__ g2g, const float* __restrict__ g2b,
                   const float* __restrict__ g2m, const float* __restrict__ g2v,
                   const float* __restrict__ gw3, const float* __restrict__ gb3,
                   int* __restrict__ route_i, float* __restrict__ route_w)
{
    int b = blockIdx.x, tid = threadIdx.x;
    __shared__ int tk[TT];
    __shared__ float feat[DD];
    __shared__ float h1[GG1];
    __shared__ float h2[GG2];
    __shared__ float lg[EE];
    if (tid < TT) tk[tid] = x[b * TT + tid];
    __syncthreads();
    if (tid < DD) {
        float s = 0.f;
        for (int t = 0; t < TT; t++) s += emb[(size_t)tk[t] * DD + tid];  // emb[0] base
        feat[tid] = s * (1.f / TT);
    }
    __syncthreads();
    for (int j = tid; j < GG1; j += 128) {
        float s = gb1[j];
        const float* wr = gw1 + (size_t)j * DD;
        for (int d = 0; d < DD; d++) s += feat[d] * wr[d];
        float y = (s - g1m[j]) / sqrtf(g1v[j] + 1e-5f) * g1g[j] + g1b[j];
        h1[j] = y > 0.f ? y : 0.f;
    }
    __syncthreads();
    for (int j = tid; j < GG2; j += 128) {
        float s = gb2[j];
        const float* wr = gw2 + (size_t)j * GG1;
        for (int d = 0; d < GG1; d++) s += h1[d] * wr[d];
        float y = (s - g2m[j]) / sqrtf(g2v[j] + 1e-5f) * g2g[j] + g2b[j];
        h2[j] = y > 0.f ? y : 0.f;
    }
    __syncthreads();
    if (tid < EE) {
        float s = gb3[tid];
        const float* wr = gw3 + (size_t)tid * GG2;
        for (int d = 0; d < GG2; d++) s += h2[d] * wr[d];
        lg[tid] = s;
    }
    __syncthreads();
    if (tid == 0) {
        int i0 = 0;
        for (int i = 1; i < EE; i++) if (lg[i] > lg[i0]) i0 = i;
        int i1 = (i0 == 0) ? 1 : 0;
        for (int i = 0; i < EE; i++) if (i != i0 && lg[i] > lg[i1]) i1 = i;
        float e1 = expf(lg[i1] - lg[i0]);
        float inv = 1.f / (1.f + e1);
        route_i[b * 2] = i0; route_i[b * 2 + 1] = i1;
        route_w[b * 2] = inv; route_w[b * 2 + 1] = e1 * inv;
    }
}

// ---------------- route: deterministic compaction, 32-padded per-expert regions ----------------
__global__ void route_kernel(const int* __restrict__ route_i, const float* __restrict__ route_w,
                             int* __restrict__ slot_b, int* __restrict__ slot_k,
                             float* __restrict__ slot_w, int* __restrict__ slot_e,
                             int* __restrict__ tile_valid)
{
    __shared__ int eid[BB * 2];
    __shared__ int cnt[EE];
    __shared__ int off[EE + 1];
    int tid = threadIdx.x;
    for (int i = tid; i < BB * 2; i += 256) eid[i] = route_i[i];
    __syncthreads();
    if (tid < EE) { int c = 0; for (int i = 0; i < BB * 2; i++) c += (eid[i] == tid); cnt[tid] = c; }
    __syncthreads();
    if (tid == 0) {
        off[0] = 0;
        for (int e = 0; e < EE; e++) off[e + 1] = off[e] + ((cnt[e] + MT - 1) / MT) * MT;
    }
    __syncthreads();
    for (int s = tid; s < SLOTS; s += 256) {
        int e2 = 0;
        if (s < off[EE]) { for (int q = 0; q < EE; q++) if (s >= off[q]) e2 = q; }
        slot_b[s] = -1; slot_k[s] = 0; slot_w[s] = 0.f; slot_e[s] = e2;
    }
    __syncthreads();
    for (int i = tid; i < BB * 2; i += 256) {
        int e2 = eid[i]; int rank = 0;
        for (int j = 0; j < i; j++) rank += (eid[j] == e2);
        int s = off[e2] + rank;
        slot_b[s] = i >> 1; slot_k[s] = i & 1; slot_w[s] = route_w[i];
    }
    __syncthreads();
    for (int m = tid; m < NTILES; m += 256) tile_valid[m] = (slot_b[m * MT] >= 0) ? 1 : 0;
}

// ---------------- fused skewed LSTM step: layer0 @ t, layer1 @ t-1 ----------------
__global__ __launch_bounds__(256)
void step_kernel(int t, const int* __restrict__ x, const float* __restrict__ embW,
                 const float* __restrict__ W0T, const float* __restrict__ W1T,
                 const float* __restrict__ bsum1,
                 const float* __restrict__ h0_in, float* __restrict__ h0_out,
                 const float* __restrict__ h1_in, float* __restrict__ h1_out,
                 float* __restrict__ c0, float* __restrict__ c1,
                 const int* __restrict__ slot_b, const int* __restrict__ slot_e,
                 const int* __restrict__ tile_valid)
{
    const int layer = blockIdx.z;
    if (layer == 0 && t >= TT) return;
    if (layer == 1 && t == 0) return;
    const int m = blockIdx.x;
    if (!tile_valid[m]) return;
    const int ny = blockIdx.y;
    const int tid = threadIdx.x;
    const int s0 = m * MT;
    const int e = slot_e[s0];

    __shared__ float bT[KC * 256];
    __shared__ float aT[KC * 36];
    __shared__ float zbuf[MT * 256];
    __shared__ int toks[MT];

    if (layer == 0 && tid < MT) {
        int b = slot_b[s0 + tid];
        toks[tid] = (b >= 0) ? x[b * TT + t] : 0;
    }

    const int K = (layer == 0) ? HH : 2 * HH;
    const float* WT = (layer == 0) ? (W0T + (size_t)e * HH * FH)
                                   : (W1T + (size_t)e * 2 * HH * FH);
    const int cg = tid & 31;
    const int rg = tid >> 5;

    float acc[4][8];
    #pragma unroll
    for (int i = 0; i < 4; i++)
        #pragma unroll
        for (int j = 0; j < 8; j++) acc[i][j] = 0.f;

    for (int kb = 0; kb < K; kb += KC) {
        __syncthreads();
        // stage B tile: bT[k][c] = WT[kb+k][gc(c)]   (16 x 256)
        #pragma unroll
        for (int it = 0; it < 4; it++) {
            int fi = it * 256 + tid;     // float4 index among 1024
            int k = fi >> 6, c4 = fi & 63;
            int c = c4 * 4;
            int gc = ((c >> 6) * HH) + ny * 64 + (c & 63);
            *(float4*)&bT[k * 256 + c] = *(const float4*)&WT[(size_t)(kb + k) * FH + gc];
        }
        // stage A tile transposed: aT[k][r]
        #pragma unroll
        for (int it = 0; it < 2; it++) {
            int fi = it * 256 + tid;
            int k = fi & 15, r = fi >> 4;
            int col = kb + k;
            float v;
            if (layer == 0) v = h0_in[(size_t)(s0 + r) * HH + col];
            else v = (col < HH) ? h0_in[(size_t)(s0 + r) * HH + col]
                                : h1_in[(size_t)(s0 + r) * HH + (col - HH)];
            aT[k * 36 + r] = v;
        }
        __syncthreads();
        #pragma unroll
        for (int k = 0; k < KC; k++) {
            float4 av = *(const float4*)&aT[k * 36 + rg * 4];
            float2 b0 = *(const float2*)&bT[k * 256 + 0 * 64 + 2 * cg];
            float2 b1 = *(const float2*)&bT[k * 256 + 1 * 64 + 2 * cg];
            float2 b2 = *(const float2*)&bT[k * 256 + 2 * 64 + 2 * cg];
            float2 b3 = *(const float2*)&bT[k * 256 + 3 * 64 + 2 * cg];
            float a[4] = {av.x, av.y, av.z, av.w};
            float bbv[8] = {b0.x, b0.y, b1.x, b1.y, b2.x, b2.y, b3.x, b3.y};
            #pragma unroll
            for (int ri = 0; ri < 4; ri++)
                #pragma unroll
                for (int ci = 0; ci < 8; ci++) acc[ri][ci] = fmaf(a[ri], bbv[ci], acc[ri][ci]);
        }
    }

    if (layer == 0) {
        #pragma unroll
        for (int ri = 0; ri < 4; ri++) {
            int r = rg * 4 + ri;
            const float* ew = embW + ((size_t)(e * VV + toks[r])) * FH;
            #pragma unroll
            for (int ci = 0; ci < 8; ci++) {
                int c = 64 * (ci >> 1) + 2 * cg + (ci & 1);
                int gc = (c >> 6) * HH + ny * 64 + (c & 63);
                acc[ri][ci] += ew[gc];
            }
        }
    }
    __syncthreads();
    #pragma unroll
    for (int ri = 0; ri < 4; ri++) {
        int r = rg * 4 + ri;
        #pragma unroll
        for (int ci = 0; ci < 8; ci++) {
            int c = 64 * (ci >> 1) + 2 * cg + (ci & 1);
            zbuf[r * 256 + c] = acc[ri][ci];
        }
    }
    __syncthreads();

    // gate phase: thread = (rq, jc), 8 rows each
    int rq = tid >> 6, jc = tid & 63;
    int col = ny * 64 + jc;
    float* cb = (layer == 0) ? c0 : c1;
    float* hb = (layer == 0) ? h0_out : h1_out;
    const float* bs = bsum1 + (size_t)e * FH;
    #pragma unroll
    for (int rr = 0; rr < 8; rr++) {
        int r = rq * 8 + rr;
        int slot = s0 + r;
        float iv = zbuf[r * 256 + jc];
        float fv = zbuf[r * 256 + 64 + jc];
        float gv = zbuf[r * 256 + 128 + jc];
        float ov = zbuf[r * 256 + 192 + jc];
        if (layer == 1) {
            iv += bs[col]; fv += bs[HH + col]; gv += bs[2 * HH + col]; ov += bs[3 * HH + col];
        }
        size_t cidx = (size_t)slot * HH + col;
        float cprev = cb[cidx];
        float ig = 1.f / (1.f + expf(-iv));
        float fg = 1.f / (1.f + expf(-fv));
        float og = 1.f / (1.f + expf(-ov));
        float cn = fg * cprev + ig * tanhf(gv);
        float hn = og * tanhf(cn);
        cb[cidx] = cn;
        hb[cidx] = hn;
    }
}

// ---------------- fc per slot, weighted ----------------
__global__ __launch_bounds__(256)
void fc_kernel(const float* __restrict__ fcw, const float* __restrict__ fcb,
               const float* __restrict__ h1f,
               const int* __restrict__ slot_b, const int* __restrict__ slot_k,
               const float* __restrict__ slot_w, const int* __restrict__ slot_e,
               float* __restrict__ wout)
{
    int s = blockIdx.x;
    int b = slot_b[s];
    if (b < 0) return;
    int tid = threadIdx.x;
    __shared__ float hv[HH];
    if (tid < HH) hv[tid] = h1f[(size_t)s * HH + tid];
    __syncthreads();
    int e = slot_e[s], kk = slot_k[s];
    float w = slot_w[s];
    for (int v = tid; v < VV; v += 256) {
        float sacc = fcb[e * VV + v];
        const float* fr = fcw + ((size_t)e * VV + v) * HH;
        #pragma unroll 4
        for (int d = 0; d < HH; d++) sacc += hv[d] * fr[d];
        wout[((size_t)b * 2 + kk) * VV + v] = w * sacc;
    }
}

__global__ void combine_kernel(const float* __restrict__ wout, float* __restrict__ out)
{
    int i = blockIdx.x * blockDim.x + threadIdx.x;
    if (i < BB * VV) {
        int b = i / VV, v = i % VV;
        out[i] = wout[((size_t)b * 2) * VV + v] + wout[((size_t)b * 2 + 1) * VV + v];
    }
}

extern "C" void kernel_launch(void* const* d_in, const int* in_sizes, int n_in,
                              void* d_out, int out_size, void* d_ws, size_t ws_size,
                              hipStream_t stream)
{
    const int*   x    = (const int*)d_in[0];
    const float* emb  = (const float*)d_in[1];
    const float* Wih0 = (const float*)d_in[2];
    const float* Whh0 = (const float*)d_in[3];
    const float* bih0 = (const float*)d_in[4];
    const float* bhh0 = (const float*)d_in[5];
    const float* Wih1 = (const float*)d_in[6];
    const float* Whh1 = (const float*)d_in[7];
    const float* bih1 = (const float*)d_in[8];
    const float* bhh1 = (const float*)d_in[9];
    const float* fcw  = (const float*)d_in[10];
    const float* fcb  = (const float*)d_in[11];
    const float* gw1  = (const float*)d_in[12];
    const float* gb1  = (const float*)d_in[13];
    const float* b1g  = (const float*)d_in[14];
    const float* b1b  = (const float*)d_in[15];
    const float* b1m  = (const float*)d_in[16];
    const float* b1v  = (const float*)d_in[17];
    const float* gw2  = (const float*)d_in[18];
    const float* gb2  = (const float*)d_in[19];
    const float* b2g  = (const float*)d_in[20];
    const float* b2b  = (const float*)d_in[21];
    const float* b2m  = (const float*)d_in[22];
    const float* b2v  = (const float*)d_in[23];
    const float* gw3  = (const float*)d_in[24];
    const float* gb3  = (const float*)d_in[25];

    float* f = (float*)d_ws;
    size_t o = 0;
    float* c0  = f + o; o += (size_t)SLOTS * HH;
    float* c1  = f + o; o += (size_t)SLOTS * HH;
    float* h0a = f + o; o += (size_t)SLOTS * HH;
    float* h1b = f + o; o += (size_t)SLOTS * HH;
    float* h0b = f + o; o += (size_t)SLOTS * HH;
    float* h1a = f + o; o += (size_t)SLOTS * HH;
    float* W0T = f + o; o += (size_t)EE * HH * FH;
    float* W1T = f + o; o += (size_t)EE * 2 * HH * FH;
    float* embW = f + o; o += (size_t)EE * VV * FH;
    float* bsum1 = f + o; o += (size_t)EE * FH;
    float* wout = f + o; o += (size_t)BB * 2 * VV;
    float* route_w = f + o; o += (size_t)BB * 2;
    float* slot_w = f + o; o += (size_t)SLOTS;
    int* ip = (int*)(f + o);
    int* route_i = ip; ip += BB * 2;
    int* slot_b = ip; ip += SLOTS;
    int* slot_k = ip; ip += SLOTS;
    int* slot_e = ip; ip += SLOTS;
    int* tile_valid = ip; ip += NTILES;

    // zero c0, c1, h0a, h1b (first four contiguous buffers)
    hipMemsetAsync(d_ws, 0, (size_t)4 * SLOTS * HH * sizeof(float), stream);

    prep_kernel<<<2048, 256, 0, stream>>>(Whh0, Wih1, Whh1, bih1, bhh1, W0T, W1T, bsum1);
    embw_kernel<<<EE * VV, 256, 0, stream>>>(emb, Wih0, bih0, bhh0, embW);
    gating_kernel<<<BB, 128, 0, stream>>>(x, emb, gw1, gb1, b1g, b1b, b1m, b1v,
                                          gw2, gb2, b2g, b2b, b2m, b2v, gw3, gb3,
                                          route_i, route_w);
    route_kernel<<<1, 256, 0, stream>>>(route_i, route_w, slot_b, slot_k, slot_w, slot_e, tile_valid);

    for (int t = 0; t <= TT; t++) {
        const float* h0i = (t & 1) ? h0b : h0a;
        float*       h0o = (t & 1) ? h0a : h0b;
        const float* h1i = (t & 1) ? h1b : h1a;
        float*       h1o = (t & 1) ? h1a : h1b;
        step_kernel<<<dim3(NTILES, 4, 2), 256, 0, stream>>>(
            t, x, embW, W0T, W1T, bsum1, h0i, h0o, h1i, h1o, c0, c1,
            slot_b, slot_e, tile_valid);
    }

    fc_kernel<<<SLOTS, 256, 0, stream>>>(fcw, fcb, h1b, slot_b, slot_k, slot_w, slot_e, wout);
    combine_kernel<<<(BB * VV + 255) / 256, 256, 0, stream>>>(wout, (float*)d_out);
}

// Round 2
// 1673.854 us; speedup vs baseline: 3.7060x; 3.7060x over previous
//
#include <hip/hip_runtime.h>
#include <hip/hip_bf16.h>
#include <math.h>

#define BB 512
#define TT 80
#define VV 80
#define DD 128
#define HH 256
#define FH 1024
#define EE 8
#define GG1 512
#define GG2 256
#define SLOTS 1280
#define MT 32
#define NTILES (SLOTS/MT)   // 40

typedef __attribute__((ext_vector_type(8))) short bf16x8;
typedef __attribute__((ext_vector_type(4))) float f32x4;

// ---------------- prep: pack weights into MFMA B-fragment layout (bf16), bias sums ----------------
// Wp layout: [e][p(64)][kb][l(64)][j(8)]  elem = W[gc][kk]
//   p = hb*16 + g*4 + ht4 ; gc = g*256 + hb*64 + ht4*16 + (l&15) ; kk = kb*32 + (l>>4)*8 + j
__global__ void prep_kernel(const float* __restrict__ Whh0, const float* __restrict__ Wih1,
                            const float* __restrict__ Whh1, const float* __restrict__ bih1,
                            const float* __restrict__ bhh1,
                            __hip_bfloat16* __restrict__ Wp0, __hip_bfloat16* __restrict__ Wp1,
                            float* __restrict__ bsum1)
{
    const long N0 = (long)EE * 64 * 8 * 512;    // 2,097,152
    const long N1 = (long)EE * 64 * 16 * 512;   // 4,194,304
    const long N2 = (long)EE * FH;
    const long ntot = N0 + N1 + N2;
    for (long idx = (long)blockIdx.x * blockDim.x + threadIdx.x; idx < ntot;
         idx += (long)gridDim.x * blockDim.x) {
        if (idx < N0) {
            long r = idx;
            int j = r & 7; r >>= 3;
            int l = r & 63; r >>= 6;
            int kb = r & 7; r >>= 3;
            int p = r & 63; r >>= 6;
            int e = (int)r;
            int g = (p >> 2) & 3, hbk = p >> 4, ht4 = p & 3;
            int gc = g * 256 + hbk * 64 + ht4 * 16 + (l & 15);
            int kk = kb * 32 + (l >> 4) * 8 + j;
            Wp0[idx] = __float2bfloat16(Whh0[((size_t)e * FH + gc) * HH + kk]);
        } else if (idx < N0 + N1) {
            long r = idx - N0;
            int j = r & 7; r >>= 3;
            int l = r & 63; r >>= 6;
            int kb = r & 15; r >>= 4;
            int p = r & 63; r >>= 6;
            int e = (int)r;
            int g = (p >> 2) & 3, hbk = p >> 4, ht4 = p & 3;
            int gc = g * 256 + hbk * 64 + ht4 * 16 + (l & 15);
            int kk = kb * 32 + (l >> 4) * 8 + j;
            float v = (kk < HH) ? Wih1[((size_t)e * FH + gc) * HH + kk]
                                : Whh1[((size_t)e * FH + gc) * HH + (kk - HH)];
            Wp1[idx - N0] = __float2bfloat16(v);
        } else {
            long i3 = idx - N0 - N1;
            bsum1[i3] = bih1[i3] + bhh1[i3];
        }
    }
}

// ---------------- embW[e][tok][1024] = emb[e,tok] @ Wih0^T + bih0 + bhh0  (fp32) ----------------
__global__ __launch_bounds__(256)
void embw_kernel(const float* __restrict__ emb, const float* __restrict__ Wih0,
                 const float* __restrict__ bih0, const float* __restrict__ bhh0,
                 float* __restrict__ embW)
{
    int e = blockIdx.x / VV, tok = blockIdx.x % VV;
    int tid = threadIdx.x;
    __shared__ float er[DD];
    if (tid < DD) er[tid] = emb[((size_t)e * VV + tok) * DD + tid];
    __syncthreads();
    for (int gc = tid; gc < FH; gc += 256) {
        float s = bih0[e * FH + gc] + bhh0[e * FH + gc];
        const float* wr = Wih0 + ((size_t)e * FH + gc) * DD;
        #pragma unroll 4
        for (int d = 0; d < DD; d++) s += er[d] * wr[d];
        embW[((size_t)e * VV + tok) * FH + gc] = s;
    }
}

// ---------------- gating: feat -> MLP -> softmax -> top2 (fp32) ----------------
__global__ __launch_bounds__(128)
void gating_kernel(const int* __restrict__ x, const float* __restrict__ emb,
                   const float* __restrict__ gw1, const float* __restrict__ gb1,
                   const float* __restrict__ g1g, const float* __restrict__ g1b,
                   const float* __restrict__ g1m, const float* __restrict__ g1v,
                   const float* __restrict__ gw2, const float* __restrict__ gb2,
                   const float* __restrict__ g2g, const float* __restrict__ g2b,
                   const float* __restrict__ g2m, const float* __restrict__ g2v,
                   const float* __restrict__ gw3, const float* __restrict__ gb3,
                   int* __restrict__ route_i, float* __restrict__ route_w)
{
    int b = blockIdx.x, tid = threadIdx.x;
    __shared__ int tk[TT];
    __shared__ float feat[DD];
    __shared__ float h1[GG1];
    __shared__ float h2[GG2];
    __shared__ float lg[EE];
    if (tid < TT) tk[tid] = x[b * TT + tid];
    __syncthreads();
    if (tid < DD) {
        float s = 0.f;
        for (int t = 0; t < TT; t++) s += emb[(size_t)tk[t] * DD + tid];
        feat[tid] = s * (1.f / TT);
    }
    __syncthreads();
    for (int j = tid; j < GG1; j += 128) {
        float s = gb1[j];
        const float* wr = gw1 + (size_t)j * DD;
        for (int d = 0; d < DD; d++) s += feat[d] * wr[d];
        float y = (s - g1m[j]) / sqrtf(g1v[j] + 1e-5f) * g1g[j] + g1b[j];
        h1[j] = y > 0.f ? y : 0.f;
    }
    __syncthreads();
    for (int j = tid; j < GG2; j += 128) {
        float s = gb2[j];
        const float* wr = gw2 + (size_t)j * GG1;
        for (int d = 0; d < GG1; d++) s += h1[d] * wr[d];
        float y = (s - g2m[j]) / sqrtf(g2v[j] + 1e-5f) * g2g[j] + g2b[j];
        h2[j] = y > 0.f ? y : 0.f;
    }
    __syncthreads();
    if (tid < EE) {
        float s = gb3[tid];
        const float* wr = gw3 + (size_t)tid * GG2;
        for (int d = 0; d < GG2; d++) s += h2[d] * wr[d];
        lg[tid] = s;
    }
    __syncthreads();
    if (tid == 0) {
        int i0 = 0;
        for (int i = 1; i < EE; i++) if (lg[i] > lg[i0]) i0 = i;
        int i1 = (i0 == 0) ? 1 : 0;
        for (int i = 0; i < EE; i++) if (i != i0 && lg[i] > lg[i1]) i1 = i;
        float e1 = expf(lg[i1] - lg[i0]);
        float inv = 1.f / (1.f + e1);
        route_i[b * 2] = i0; route_i[b * 2 + 1] = i1;
        route_w[b * 2] = inv; route_w[b * 2 + 1] = e1 * inv;
    }
}

// ---------------- route: wave-ballot compaction, 32-padded per-expert regions ----------------
__global__ __launch_bounds__(1024)
void route_kernel(const int* __restrict__ route_i, const float* __restrict__ route_w,
                  int* __restrict__ slot_b, int* __restrict__ slot_k,
                  float* __restrict__ slot_w, int* __restrict__ slot_e,
                  int* __restrict__ tile_valid)
{
    __shared__ int wcnt[16][EE];
    __shared__ int cnt[EE];
    __shared__ int off[EE + 1];
    int tid = threadIdx.x;
    int lane = tid & 63, wv = tid >> 6;
    int e = route_i[tid];
    unsigned long long below = (1ull << lane) - 1ull;
    int rankw = 0;
    #pragma unroll
    for (int q = 0; q < EE; q++) {
        unsigned long long m = __ballot(e == q);
        if (q == e) rankw = __popcll(m & below);
        if (lane == 0) wcnt[wv][q] = __popcll(m);
    }
    __syncthreads();
    if (tid < EE) {
        int c = 0;
        for (int w2 = 0; w2 < 16; w2++) c += wcnt[w2][tid];
        cnt[tid] = c;
    }
    __syncthreads();
    if (tid == 0) {
        off[0] = 0;
        for (int q = 0; q < EE; q++) off[q + 1] = off[q] + ((cnt[q] + MT - 1) / MT) * MT;
    }
    __syncthreads();
    for (int s = tid; s < SLOTS; s += 1024) {
        int e2 = 0;
        if (s < off[EE]) { for (int q = 0; q < EE; q++) if (s >= off[q]) e2 = q; }
        slot_b[s] = -1; slot_k[s] = 0; slot_w[s] = 0.f; slot_e[s] = e2;
    }
    __syncthreads();
    int rank = rankw;
    for (int w2 = 0; w2 < wv; w2++) rank += wcnt[w2][e];
    int s = off[e] + rank;
    slot_b[s] = tid >> 1; slot_k[s] = tid & 1; slot_w[s] = route_w[tid];
    __syncthreads();
    for (int m2 = tid; m2 < NTILES; m2 += 1024) tile_valid[m2] = (slot_b[m2 * MT] >= 0) ? 1 : 0;
}

// ---------------- fused skewed MFMA LSTM step: layer0 @ t, layer1 @ t-1 ----------------
// block: 256 thr = 4 waves; tile M=32 slots x 64 hidden cols (=256 packed gate cols)
// wave w owns gate w for all 4 hidden sub-tiles; z exchanged via LDS for the gate phase.
__global__ __launch_bounds__(256)
void step_kernel(int t, const int* __restrict__ x, const float* __restrict__ embW,
                 const __hip_bfloat16* __restrict__ Wp0, const __hip_bfloat16* __restrict__ Wp1,
                 const float* __restrict__ bsum1,
                 const __hip_bfloat16* __restrict__ h0_in, __hip_bfloat16* __restrict__ h0_out,
                 const __hip_bfloat16* __restrict__ h1_in, __hip_bfloat16* __restrict__ h1_out,
                 float* __restrict__ c0, float* __restrict__ c1,
                 const int* __restrict__ slot_b, const int* __restrict__ slot_e,
                 const int* __restrict__ tile_valid)
{
    const int layer = blockIdx.z;
    if (layer == 0 && t >= TT) return;
    if (layer == 1 && t == 0) return;
    const int m = blockIdx.x;
    if (!tile_valid[m]) return;
    const int hb = blockIdx.y;          // 0..3 -> 64 hidden cols
    const int tid = threadIdx.x;
    const int lane = tid & 63;
    const int w = tid >> 6;             // wave id == gate id
    const int s0 = m * MT;
    const int e = slot_e[s0];
    const int r15 = lane & 15;
    const int kh = lane >> 4;           // 0..3

    __shared__ float zbuf[32 * 260];
    __shared__ int toks[MT];
    if (layer == 0 && tid < MT) {
        int b = slot_b[s0 + tid];
        toks[tid] = (b >= 0) ? x[b * TT + t] : 0;
    }

    const int KB = (layer == 0) ? 8 : 16;
    const size_t pstride = (size_t)KB * 512;
    const __hip_bfloat16* Wp = (layer == 0)
        ? (Wp0 + (size_t)(e * 64 + hb * 16 + w * 4) * 8 * 512)
        : (Wp1 + (size_t)(e * 64 + hb * 16 + w * 4) * 16 * 512);

    f32x4 acc[2][4];
    #pragma unroll
    for (int i = 0; i < 2; i++)
        #pragma unroll
        for (int j = 0; j < 4; j++) acc[i][j] = (f32x4){0.f, 0.f, 0.f, 0.f};

    const size_t aoff0 = (size_t)(s0 + r15) * HH;
    const size_t aoff1 = (size_t)(s0 + 16 + r15) * HH;

    #pragma unroll 4
    for (int kb = 0; kb < KB; kb++) {
        const int koff = kb * 32 + kh * 8;
        const __hip_bfloat16* asrc; int ko;
        if (layer == 1 && koff >= HH) { asrc = h1_in; ko = koff - HH; }
        else { asrc = h0_in; ko = koff; }
        bf16x8 a0 = *(const bf16x8*)(asrc + aoff0 + ko);
        bf16x8 a1 = *(const bf16x8*)(asrc + aoff1 + ko);
        const __hip_bfloat16* wb = Wp + (size_t)kb * 512 + (size_t)lane * 8;
        bf16x8 b0 = *(const bf16x8*)(wb);
        bf16x8 b1 = *(const bf16x8*)(wb + pstride);
        bf16x8 b2 = *(const bf16x8*)(wb + 2 * pstride);
        bf16x8 b3 = *(const bf16x8*)(wb + 3 * pstride);
        acc[0][0] = __builtin_amdgcn_mfma_f32_16x16x32_bf16(a0, b0, acc[0][0], 0, 0, 0);
        acc[0][1] = __builtin_amdgcn_mfma_f32_16x16x32_bf16(a0, b1, acc[0][1], 0, 0, 0);
        acc[0][2] = __builtin_amdgcn_mfma_f32_16x16x32_bf16(a0, b2, acc[0][2], 0, 0, 0);
        acc[0][3] = __builtin_amdgcn_mfma_f32_16x16x32_bf16(a0, b3, acc[0][3], 0, 0, 0);
        acc[1][0] = __builtin_amdgcn_mfma_f32_16x16x32_bf16(a1, b0, acc[1][0], 0, 0, 0);
        acc[1][1] = __builtin_amdgcn_mfma_f32_16x16x32_bf16(a1, b1, acc[1][1], 0, 0, 0);
        acc[1][2] = __builtin_amdgcn_mfma_f32_16x16x32_bf16(a1, b2, acc[1][2], 0, 0, 0);
        acc[1][3] = __builtin_amdgcn_mfma_f32_16x16x32_bf16(a1, b3, acc[1][3], 0, 0, 0);
    }

    // scatter z to LDS: C frag mapping col=lane&15, row=(lane>>4)*4+reg
    #pragma unroll
    for (int rt = 0; rt < 2; rt++)
        #pragma unroll
        for (int ct = 0; ct < 4; ct++)
            #pragma unroll
            for (int reg = 0; reg < 4; reg++) {
                int row = rt * 16 + kh * 4 + reg;
                zbuf[row * 260 + w * 64 + ct * 16 + r15] = acc[rt][ct][reg];
            }
    __syncthreads();

    // gate phase: thread -> (rq, col); 8 rows each
    const int col = tid & 63;
    const int rq = tid >> 6;
    const int hcol = hb * 64 + col;
    float* cb = (layer == 0) ? c0 : c1;
    __hip_bfloat16* hob = (layer == 0) ? h0_out : h1_out;
    #pragma unroll
    for (int rr = 0; rr < 8; rr++) {
        int r = rq * 8 + rr;
        int slot = s0 + r;
        float iv = zbuf[r * 260 + col];
        float fv = zbuf[r * 260 + 64 + col];
        float gv = zbuf[r * 260 + 128 + col];
        float ov = zbuf[r * 260 + 192 + col];
        if (layer == 0) {
            const float* ew = embW + ((size_t)(e * VV + toks[r])) * FH;
            iv += ew[hcol]; fv += ew[HH + hcol]; gv += ew[2 * HH + hcol]; ov += ew[3 * HH + hcol];
        } else {
            const float* bs = bsum1 + (size_t)e * FH;
            iv += bs[hcol]; fv += bs[HH + hcol]; gv += bs[2 * HH + hcol]; ov += bs[3 * HH + hcol];
        }
        size_t ci = (size_t)slot * HH + hcol;
        float cp = cb[ci];
        float ig = 1.f / (1.f + expf(-iv));
        float fg = 1.f / (1.f + expf(-fv));
        float og = 1.f / (1.f + expf(-ov));
        float cn = fg * cp + ig * tanhf(gv);
        cb[ci] = cn;
        hob[ci] = __float2bfloat16(og * tanhf(cn));
    }
}

// ---------------- fc per slot, weighted (fp32 accum, bf16 h input) ----------------
__global__ __launch_bounds__(256)
void fc_kernel(const float* __restrict__ fcw, const float* __restrict__ fcb,
               const __hip_bfloat16* __restrict__ h1f,
               const int* __restrict__ slot_b, const int* __restrict__ slot_k,
               const float* __restrict__ slot_w, const int* __restrict__ slot_e,
               float* __restrict__ wout)
{
    int s = blockIdx.x;
    int b = slot_b[s];
    if (b < 0) return;
    int tid = threadIdx.x;
    __shared__ float hv[HH];
    if (tid < HH) hv[tid] = __bfloat162float(h1f[(size_t)s * HH + tid]);
    __syncthreads();
    int e = slot_e[s], kk = slot_k[s];
    float w = slot_w[s];
    for (int v = tid; v < VV; v += 256) {
        float sacc = fcb[e * VV + v];
        const float* fr = fcw + ((size_t)e * VV + v) * HH;
        #pragma unroll 4
        for (int d = 0; d < HH; d++) sacc += hv[d] * fr[d];
        wout[((size_t)b * 2 + kk) * VV + v] = w * sacc;
    }
}

__global__ void combine_kernel(const float* __restrict__ wout, float* __restrict__ out)
{
    int i = blockIdx.x * blockDim.x + threadIdx.x;
    if (i < BB * VV) {
        int b = i / VV, v = i % VV;
        out[i] = wout[((size_t)b * 2) * VV + v] + wout[((size_t)b * 2 + 1) * VV + v];
    }
}

extern "C" void kernel_launch(void* const* d_in, const int* in_sizes, int n_in,
                              void* d_out, int out_size, void* d_ws, size_t ws_size,
                              hipStream_t stream)
{
    const int*   x    = (const int*)d_in[0];
    const float* emb  = (const float*)d_in[1];
    const float* Wih0 = (const float*)d_in[2];
    const float* Whh0 = (const float*)d_in[3];
    const float* bih0 = (const float*)d_in[4];
    const float* bhh0 = (const float*)d_in[5];
    const float* Wih1 = (const float*)d_in[6];
    const float* Whh1 = (const float*)d_in[7];
    const float* bih1 = (const float*)d_in[8];
    const float* bhh1 = (const float*)d_in[9];
    const float* fcw  = (const float*)d_in[10];
    const float* fcb  = (const float*)d_in[11];
    const float* gw1  = (const float*)d_in[12];
    const float* gb1  = (const float*)d_in[13];
    const float* b1g  = (const float*)d_in[14];
    const float* b1b  = (const float*)d_in[15];
    const float* b1m  = (const float*)d_in[16];
    const float* b1v  = (const float*)d_in[17];
    const float* gw2  = (const float*)d_in[18];
    const float* gb2  = (const float*)d_in[19];
    const float* b2g  = (const float*)d_in[20];
    const float* b2b  = (const float*)d_in[21];
    const float* b2m  = (const float*)d_in[22];
    const float* b2v  = (const float*)d_in[23];
    const float* gw3  = (const float*)d_in[24];
    const float* gb3  = (const float*)d_in[25];

    char* base = (char*)d_ws;
    size_t o = 0;
    const size_t NC = (size_t)SLOTS * HH;
    float* c0 = (float*)(base + o); o += NC * 4;
    float* c1 = (float*)(base + o); o += NC * 4;
    __hip_bfloat16* h0a = (__hip_bfloat16*)(base + o); o += NC * 2;
    __hip_bfloat16* h1b = (__hip_bfloat16*)(base + o); o += NC * 2;
    const size_t zero_bytes = o;   // c0,c1,h0a,h1b contiguous
    __hip_bfloat16* h0b = (__hip_bfloat16*)(base + o); o += NC * 2;
    __hip_bfloat16* h1a = (__hip_bfloat16*)(base + o); o += NC * 2;
    __hip_bfloat16* Wp0 = (__hip_bfloat16*)(base + o); o += (size_t)EE * 64 * 8 * 512 * 2;
    __hip_bfloat16* Wp1 = (__hip_bfloat16*)(base + o); o += (size_t)EE * 64 * 16 * 512 * 2;
    float* embW  = (float*)(base + o); o += (size_t)EE * VV * FH * 4;
    float* bsum1 = (float*)(base + o); o += (size_t)EE * FH * 4;
    float* wout  = (float*)(base + o); o += (size_t)BB * 2 * VV * 4;
    float* route_w = (float*)(base + o); o += (size_t)BB * 2 * 4;
    float* slot_w  = (float*)(base + o); o += (size_t)SLOTS * 4;
    int* route_i = (int*)(base + o); o += (size_t)BB * 2 * 4;
    int* slot_b  = (int*)(base + o); o += (size_t)SLOTS * 4;
    int* slot_k  = (int*)(base + o); o += (size_t)SLOTS * 4;
    int* slot_e  = (int*)(base + o); o += (size_t)SLOTS * 4;
    int* tile_valid = (int*)(base + o); o += (size_t)NTILES * 4;

    hipMemsetAsync(d_ws, 0, zero_bytes, stream);

    prep_kernel<<<4096, 256, 0, stream>>>(Whh0, Wih1, Whh1, bih1, bhh1, Wp0, Wp1, bsum1);
    embw_kernel<<<EE * VV, 256, 0, stream>>>(emb, Wih0, bih0, bhh0, embW);
    gating_kernel<<<BB, 128, 0, stream>>>(x, emb, gw1, gb1, b1g, b1b, b1m, b1v,
                                          gw2, gb2, b2g, b2b, b2m, b2v, gw3, gb3,
                                          route_i, route_w);
    route_kernel<<<1, 1024, 0, stream>>>(route_i, route_w, slot_b, slot_k, slot_w, slot_e, tile_valid);

    for (int t = 0; t <= TT; t++) {
        const __hip_bfloat16* h0i = (t & 1) ? h0b : h0a;
        __hip_bfloat16*       h0o = (t & 1) ? h0a : h0b;
        const __hip_bfloat16* h1i = (t & 1) ? h1b : h1a;
        __hip_bfloat16*       h1o = (t & 1) ? h1a : h1b;
        step_kernel<<<dim3(NTILES, 4, 2), 256, 0, stream>>>(
            t, x, embW, Wp0, Wp1, bsum1, h0i, h0o, h1i, h1o, c0, c1,
            slot_b, slot_e, tile_valid);
    }

    fc_kernel<<<SLOTS, 256, 0, stream>>>(fcw, fcb, h1b, slot_b, slot_k, slot_w, slot_e, wout);
    combine_kernel<<<(BB * VV + 255) / 256, 256, 0, stream>>>(wout, (float*)d_out);
}

// Round 3
// 1637.989 us; speedup vs baseline: 3.7871x; 1.0219x over previous
//
#include <hip/hip_runtime.h>
#include <hip/hip_bf16.h>
#include <math.h>

#define BB 512
#define TT 80
#define VV 80
#define DD 128
#define HH 256
#define FH 1024
#define EE 8
#define GG1 512
#define GG2 256
#define MT 16
#define NT 72
#define SLOTS (NT*MT)   // 1152

typedef __attribute__((ext_vector_type(8))) short bf16x8;
typedef __attribute__((ext_vector_type(4))) float f32x4;

__device__ __forceinline__ float bf2f(unsigned short u) {
    unsigned int v = ((unsigned int)u) << 16;
    return __builtin_bit_cast(float, v);
}
__device__ __forceinline__ unsigned short f2bf(float f) {
    __hip_bfloat16 h = __float2bfloat16(f);
    return __builtin_bit_cast(unsigned short, h);
}
__device__ __forceinline__ float sigm(float x) { return 1.f / (1.f + __expf(-x)); }
__device__ __forceinline__ float tanh_f(float x) {
    float ax = fabsf(x);
    float r = 1.f - 2.f / (__expf(2.f * ax) + 1.f);
    return x < 0.f ? -r : r;
}

// ---------------- prep: pack Whh0/Whh1 (recurrent, per-wave frag layout) + Wih1 (GEMM layout) ----------------
// WR: [e][w(8)][frag=kb*8+nf (64)][lane(64)][j(8)]
//     elem = W[gc][kk], gc=(nf>>1)*256 + w*32 + (nf&1)*16 + (l&15), kk=kb*32+(l>>4)*8+j
// WG: [e][nf(64)][kb(8)][lane(64)][j(8)]  elem = Wih1[gc=nf*16+(l&15)][kk=kb*32+(l>>4)*8+j]
__global__ void prep_kernel(const float* __restrict__ Whh0, const float* __restrict__ Wih1,
                            const float* __restrict__ Whh1,
                            const float* __restrict__ bih1, const float* __restrict__ bhh1,
                            unsigned short* __restrict__ WR0, unsigned short* __restrict__ WR1,
                            unsigned short* __restrict__ WG, float* __restrict__ bsum1)
{
    const int NW = EE * 8 * 64 * 512;  // 2097152
    const int ntot = 3 * NW + EE * FH;
    for (int idx = blockIdx.x * blockDim.x + threadIdx.x; idx < ntot;
         idx += gridDim.x * blockDim.x) {
        if (idx < 2 * NW) {
            int p = (idx >= NW) ? idx - NW : idx;
            const float* W = (idx >= NW) ? Whh1 : Whh0;
            int j = p & 7, l = (p >> 3) & 63, frag = (p >> 9) & 63, w = (p >> 15) & 7, e = p >> 18;
            int kb = frag >> 3, nf = frag & 7;
            int gc = (nf >> 1) * 256 + w * 32 + (nf & 1) * 16 + (l & 15);
            int kk = kb * 32 + (l >> 4) * 8 + j;
            unsigned short v = f2bf(W[((size_t)e * FH + gc) * HH + kk]);
            if (idx >= NW) WR1[p] = v; else WR0[p] = v;
        } else if (idx < 3 * NW) {
            int p = idx - 2 * NW;
            int j = p & 7, l = (p >> 3) & 63, kb = (p >> 9) & 7, nf = (p >> 12) & 63, e = p >> 18;
            int gc = nf * 16 + (l & 15);
            int kk = kb * 32 + (l >> 4) * 8 + j;
            WG[p] = f2bf(Wih1[((size_t)e * FH + gc) * HH + kk]);
        } else {
            int p = idx - 3 * NW;
            bsum1[p] = bih1[p] + bhh1[p];
        }
    }
}

// ---------------- embW[e][tok][1024] bf16 = emb[e,tok] @ Wih0^T + bih0 + bhh0 ----------------
__global__ __launch_bounds__(256)
void embw_kernel(const float* __restrict__ emb, const float* __restrict__ Wih0,
                 const float* __restrict__ bih0, const float* __restrict__ bhh0,
                 unsigned short* __restrict__ embW)
{
    const int e = blockIdx.x, ch = blockIdx.y;
    const int tid = threadIdx.x;
    const int gc = ch * 256 + tid;
    __shared__ float er[DD * VV];  // [d][tok]
    for (int i = tid; i < VV * DD; i += 256) {
        int tok = i >> 7, d = i & 127;
        er[d * VV + tok] = emb[((size_t)e * VV + tok) * DD + d];
    }
    __syncthreads();
    float acc[VV];
    #pragma unroll
    for (int v = 0; v < VV; v++) acc[v] = 0.f;
    const float* wr = Wih0 + ((size_t)e * FH + gc) * DD;
    for (int d = 0; d < DD; d++) {
        float wv = wr[d];
        #pragma unroll
        for (int v4 = 0; v4 < VV; v4 += 4) {
            float4 ev = *(const float4*)&er[d * VV + v4];
            acc[v4] += ev.x * wv; acc[v4 + 1] += ev.y * wv;
            acc[v4 + 2] += ev.z * wv; acc[v4 + 3] += ev.w * wv;
        }
    }
    float bias = bih0[e * FH + gc] + bhh0[e * FH + gc];
    #pragma unroll 4
    for (int v = 0; v < VV; v++)
        embW[((size_t)e * VV + v) * FH + gc] = f2bf(acc[v] + bias);
}

// ---------------- gating: feat -> MLP -> softmax -> top2 (fp32) ----------------
__global__ __launch_bounds__(128)
void gating_kernel(const int* __restrict__ x, const float* __restrict__ emb,
                   const float* __restrict__ gw1, const float* __restrict__ gb1,
                   const float* __restrict__ g1g, const float* __restrict__ g1b,
                   const float* __restrict__ g1m, const float* __restrict__ g1v,
                   const float* __restrict__ gw2, const float* __restrict__ gb2,
                   const float* __restrict__ g2g, const float* __restrict__ g2b,
                   const float* __restrict__ g2m, const float* __restrict__ g2v,
                   const float* __restrict__ gw3, const float* __restrict__ gb3,
                   int* __restrict__ route_i, float* __restrict__ route_w)
{
    int b = blockIdx.x, tid = threadIdx.x;
    __shared__ int tk[TT];
    __shared__ float feat[DD];
    __shared__ float h1[GG1];
    __shared__ float h2[GG2];
    __shared__ float lg[EE];
    if (tid < TT) tk[tid] = x[b * TT + tid];
    __syncthreads();
    if (tid < DD) {
        float s = 0.f;
        for (int t = 0; t < TT; t++) s += emb[(size_t)tk[t] * DD + tid];
        feat[tid] = s * (1.f / TT);
    }
    __syncthreads();
    for (int j = tid; j < GG1; j += 128) {
        float s = gb1[j];
        const float* wr = gw1 + (size_t)j * DD;
        for (int d = 0; d < DD; d++) s += feat[d] * wr[d];
        float y = (s - g1m[j]) / sqrtf(g1v[j] + 1e-5f) * g1g[j] + g1b[j];
        h1[j] = y > 0.f ? y : 0.f;
    }
    __syncthreads();
    for (int j = tid; j < GG2; j += 128) {
        float s = gb2[j];
        const float* wr = gw2 + (size_t)j * GG1;
        for (int d = 0; d < GG1; d++) s += h1[d] * wr[d];
        float y = (s - g2m[j]) / sqrtf(g2v[j] + 1e-5f) * g2g[j] + g2b[j];
        h2[j] = y > 0.f ? y : 0.f;
    }
    __syncthreads();
    if (tid < EE) {
        float s = gb3[tid];
        const float* wr = gw3 + (size_t)tid * GG2;
        for (int d = 0; d < GG2; d++) s += h2[d] * wr[d];
        lg[tid] = s;
    }
    __syncthreads();
    if (tid == 0) {
        int i0 = 0;
        for (int i = 1; i < EE; i++) if (lg[i] > lg[i0]) i0 = i;
        int i1 = (i0 == 0) ? 1 : 0;
        for (int i = 0; i < EE; i++) if (i != i0 && lg[i] > lg[i1]) i1 = i;
        float e1 = expf(lg[i1] - lg[i0]);
        float inv = 1.f / (1.f + e1);
        route_i[b * 2] = i0; route_i[b * 2 + 1] = i1;
        route_w[b * 2] = inv; route_w[b * 2 + 1] = e1 * inv;
    }
}

// ---------------- route: wave-ballot compaction, 16-padded per-expert regions ----------------
__global__ __launch_bounds__(1024)
void route_kernel(const int* __restrict__ route_i, const float* __restrict__ route_w,
                  int* __restrict__ slot_b, int* __restrict__ slot_k,
                  float* __restrict__ slot_w, int* __restrict__ slot_e)
{
    __shared__ int wcnt[16][EE];
    __shared__ int cnt[EE];
    __shared__ int off[EE + 1];
    int tid = threadIdx.x;
    int lane = tid & 63, wv = tid >> 6;
    int e = route_i[tid];
    unsigned long long below = (1ull << lane) - 1ull;
    int rankw = 0;
    #pragma unroll
    for (int q = 0; q < EE; q++) {
        unsigned long long m = __ballot(e == q);
        if (q == e) rankw = __popcll(m & below);
        if (lane == 0) wcnt[wv][q] = __popcll(m);
    }
    __syncthreads();
    if (tid < EE) {
        int c = 0;
        for (int w2 = 0; w2 < 16; w2++) c += wcnt[w2][tid];
        cnt[tid] = c;
    }
    __syncthreads();
    if (tid == 0) {
        off[0] = 0;
        for (int q = 0; q < EE; q++) off[q + 1] = off[q] + ((cnt[q] + MT - 1) / MT) * MT;
    }
    __syncthreads();
    for (int s = tid; s < SLOTS; s += 1024) {
        int e2 = 0;
        if (s < off[EE]) { for (int q = 0; q < EE; q++) if (s >= off[q]) e2 = q; }
        slot_b[s] = -1; slot_k[s] = 0; slot_w[s] = 0.f; slot_e[s] = e2;
    }
    __syncthreads();
    int rank = rankw;
    for (int w2 = 0; w2 < wv; w2++) rank += wcnt[w2][e];
    int s = off[e] + rank;
    slot_b[s] = tid >> 1; slot_k[s] = tid & 1; slot_w[s] = route_w[tid];
}

// ---------------- persistent LSTM chunk kernel (one block = 16 slots, full width, tcount steps) ----
// 512 thr = 8 waves; wave w owns hcols [w*32, w*32+32) x 4 gates (nf = g*2+hc).
// h in LDS (frag layout), c in registers. Weights: kb0-1 VGPR-resident, kb2-7 streamed.
template<int LAYER>
__global__ __launch_bounds__(512, 2)
void lstm_kernel(int t0, int tcount,
                 const unsigned short* __restrict__ WR,
                 const unsigned short* __restrict__ embW,
                 const unsigned short* __restrict__ zin1,
                 const float* __restrict__ bsum1,
                 const int* __restrict__ x,
                 const int* __restrict__ slot_b, const int* __restrict__ slot_e,
                 unsigned short* __restrict__ h0seq,
                 float* __restrict__ h1f,
                 float* __restrict__ cst, unsigned short* __restrict__ hsv)
{
    const int tile = blockIdx.x;
    if (slot_b[tile * MT] < 0) return;
    const int tid = threadIdx.x;
    const int lane = tid & 63;
    const int w = tid >> 6;
    const int e = slot_e[tile * MT];

    __shared__ unsigned short hbuf[4096];        // [kb][lane][8]
    __shared__ unsigned short in_lds[16 * 1024]; // [row][gcol]
    __shared__ float bsum_lds[1024];
    __shared__ int toks[TT * 16];

    if (LAYER == 0) {
        for (int i = tid; i < tcount * 16; i += 512) {
            int t = i >> 4, r = i & 15;
            int b = slot_b[tile * MT + r];
            toks[i] = (b >= 0) ? x[b * TT + t0 + t] : 0;
        }
    } else {
        bsum_lds[tid] = bsum1[e * FH + tid];
        bsum_lds[tid + 512] = bsum1[e * FH + 512 + tid];
    }

    if (t0 == 0) {
        *(f32x4*)&hbuf[tid * 8] = (f32x4){0.f, 0.f, 0.f, 0.f};
    } else {
        *(bf16x8*)&hbuf[tid * 8] = *(const bf16x8*)(hsv + (size_t)tile * 4096 + tid * 8);
    }
    float c[8];
    if (t0 == 0) {
        #pragma unroll
        for (int i = 0; i < 8; i++) c[i] = 0.f;
    } else {
        f32x4 v0 = *(const f32x4*)&cst[((size_t)(tile * 512 + tid)) * 8];
        f32x4 v1 = *(const f32x4*)&cst[((size_t)(tile * 512 + tid)) * 8 + 4];
        c[0]=v0[0]; c[1]=v0[1]; c[2]=v0[2]; c[3]=v0[3];
        c[4]=v1[0]; c[5]=v1[1]; c[6]=v1[2]; c[7]=v1[3];
    }

    const unsigned short* WB = WR + ((size_t)(e * 8 + w) * 64) * 512 + lane * 8;
    bf16x8 wres[16];
    #pragma unroll
    for (int i = 0; i < 16; i++) wres[i] = *(const bf16x8*)(WB + i * 512);

    __syncthreads();

    const int row_s = tid >> 5;
    const int so = (tid & 31) * 32;
    const int l15 = lane & 15;
    const int q = lane >> 4;

    for (int t = 0; t < tcount; t++) {
        // stage this step's input row segment (latency hidden under MFMA)
        const unsigned short* src;
        if (LAYER == 0) {
            int tok = toks[t * 16 + row_s];
            src = embW + ((size_t)e * VV + tok) * FH + so;
        } else {
            src = zin1 + (((size_t)(tile * tcount + t)) * 16 + row_s) * FH + so;
        }
        bf16x8 s0 = *(const bf16x8*)(src);
        bf16x8 s1 = *(const bf16x8*)(src + 8);
        bf16x8 s2 = *(const bf16x8*)(src + 16);
        bf16x8 s3 = *(const bf16x8*)(src + 24);

        // A fragments from h LDS
        bf16x8 a[8];
        #pragma unroll
        for (int kb = 0; kb < 8; kb++) a[kb] = *(const bf16x8*)&hbuf[(kb * 64 + lane) * 8];

        f32x4 acc[8];
        #pragma unroll
        for (int nf = 0; nf < 8; nf++) acc[nf] = (f32x4){0.f, 0.f, 0.f, 0.f};

        #pragma unroll
        for (int kb = 0; kb < 2; kb++) {
            #pragma unroll
            for (int nf = 0; nf < 8; nf++)
                acc[nf] = __builtin_amdgcn_mfma_f32_16x16x32_bf16(a[kb], wres[kb * 8 + nf], acc[nf], 0, 0, 0);
        }
        #pragma unroll
        for (int kb = 2; kb < 8; kb++) {
            bf16x8 ws[8];
            #pragma unroll
            for (int nf = 0; nf < 8; nf++) ws[nf] = *(const bf16x8*)(WB + (kb * 8 + nf) * 512);
            #pragma unroll
            for (int nf = 0; nf < 8; nf++)
                acc[nf] = __builtin_amdgcn_mfma_f32_16x16x32_bf16(a[kb], ws[nf], acc[nf], 0, 0, 0);
        }

        // commit staged inputs to LDS
        {
            bf16x8* ild = (bf16x8*)&in_lds[row_s * 1024 + so];
            ild[0] = s0; ild[1] = s1; ild[2] = s2; ild[3] = s3;
        }
        __syncthreads();   // in_lds ready; all hbuf A-reads done

        // gate phase: lane owns 4 slots x 2 hcols, all 4 gates in-lane
        #pragma unroll
        for (int reg = 0; reg < 4; reg++) {
            int row = q * 4 + reg;
            #pragma unroll
            for (int hc = 0; hc < 2; hc++) {
                int gb = w * 32 + hc * 16 + l15;
                const unsigned short* ir = &in_lds[row * 1024 + gb];
                float iv = acc[0 + hc][reg] + bf2f(ir[0]);
                float fv = acc[2 + hc][reg] + bf2f(ir[256]);
                float gv = acc[4 + hc][reg] + bf2f(ir[512]);
                float ov = acc[6 + hc][reg] + bf2f(ir[768]);
                if (LAYER == 1) {
                    iv += bsum_lds[gb]; fv += bsum_lds[256 + gb];
                    gv += bsum_lds[512 + gb]; ov += bsum_lds[768 + gb];
                }
                float cp = c[reg * 2 + hc];
                float cn = sigm(fv) * cp + sigm(iv) * tanh_f(gv);
                float hn = sigm(ov) * tanh_f(cn);
                c[reg * 2 + hc] = cn;
                int lane2 = row + ((hc * 2 + (l15 >> 3)) << 4);
                hbuf[((w << 6) + lane2) * 8 + (lane & 7)] = f2bf(hn);
                if (LAYER == 1 && t0 + t == TT - 1)
                    h1f[((size_t)(tile * MT + row)) * HH + w * 32 + hc * 16 + l15] = hn;
            }
        }
        __syncthreads();   // hbuf[t] complete

        if (LAYER == 0) {
            bf16x8 hv = *(const bf16x8*)&hbuf[tid * 8];
            *(bf16x8*)(h0seq + ((size_t)(tile * tcount + t)) * 4096 + tid * 8) = hv;
        }
    }

    // save chunk state
    f32x4 v0, v1;
    v0[0]=c[0]; v0[1]=c[1]; v0[2]=c[2]; v0[3]=c[3];
    v1[0]=c[4]; v1[1]=c[5]; v1[2]=c[6]; v1[3]=c[7];
    *(f32x4*)&cst[((size_t)(tile * 512 + tid)) * 8] = v0;
    *(f32x4*)&cst[((size_t)(tile * 512 + tid)) * 8 + 4] = v1;
    *(bf16x8*)(hsv + (size_t)tile * 4096 + tid * 8) = *(const bf16x8*)&hbuf[tid * 8];
}

// ---------------- zin1[tile][tloc][slot][1024] = h0seq @ Wih1^T (batched MFMA GEMM) ----------------
__global__ __launch_bounds__(256, 2)
void gemm_zin(int tcount,
              const unsigned short* __restrict__ h0seq,
              const unsigned short* __restrict__ WG,
              const int* __restrict__ slot_b, const int* __restrict__ slot_e,
              unsigned short* __restrict__ zin1)
{
    const int tile = blockIdx.x;
    if (slot_b[tile * MT] < 0) return;
    const int tch = blockIdx.y, nch = blockIdx.z;
    const int tid = threadIdx.x, lane = tid & 63, w = tid >> 6;
    const int e = slot_e[tile * MT];
    __shared__ unsigned short Abuf[32768];  // 8 tloc x [kb][lane][8] = 64 KB
    const unsigned short* Asrc = h0seq + ((size_t)(tile * tcount + tch * 8)) * 4096;
    #pragma unroll
    for (int i = 0; i < 16; i++) {
        int o = (i * 256 + tid) * 8;
        *(bf16x8*)&Abuf[o] = *(const bf16x8*)&Asrc[o];
    }
    __syncthreads();
    const unsigned short* Bp = WG + ((size_t)(e * 64 + nch * 16 + w * 4)) * 4096 + lane * 8;
    f32x4 acc[8][4];
    #pragma unroll
    for (int mf = 0; mf < 8; mf++)
        #pragma unroll
        for (int nfi = 0; nfi < 4; nfi++) acc[mf][nfi] = (f32x4){0.f, 0.f, 0.f, 0.f};
    #pragma unroll
    for (int kb = 0; kb < 8; kb++) {
        bf16x8 b0 = *(const bf16x8*)(Bp + 0 * 4096 + kb * 512);
        bf16x8 b1 = *(const bf16x8*)(Bp + 1 * 4096 + kb * 512);
        bf16x8 b2 = *(const bf16x8*)(Bp + 2 * 4096 + kb * 512);
        bf16x8 b3 = *(const bf16x8*)(Bp + 3 * 4096 + kb * 512);
        #pragma unroll
        for (int mf = 0; mf < 8; mf++) {
            bf16x8 a = *(const bf16x8*)&Abuf[(mf * 8 + kb) * 512 + lane * 8];
            acc[mf][0] = __builtin_amdgcn_mfma_f32_16x16x32_bf16(a, b0, acc[mf][0], 0, 0, 0);
            acc[mf][1] = __builtin_amdgcn_mfma_f32_16x16x32_bf16(a, b1, acc[mf][1], 0, 0, 0);
            acc[mf][2] = __builtin_amdgcn_mfma_f32_16x16x32_bf16(a, b2, acc[mf][2], 0, 0, 0);
            acc[mf][3] = __builtin_amdgcn_mfma_f32_16x16x32_bf16(a, b3, acc[mf][3], 0, 0, 0);
        }
    }
    const int q = lane >> 4, l15 = lane & 15;
    #pragma unroll
    for (int mf = 0; mf < 8; mf++) {
        size_t rowbase = ((size_t)(tile * tcount + tch * 8 + mf)) * 16;
        #pragma unroll
        for (int nfi = 0; nfi < 4; nfi++) {
            int col = (nch * 16 + w * 4 + nfi) * 16 + l15;
            #pragma unroll
            for (int reg = 0; reg < 4; reg++) {
                int row = q * 4 + reg;
                zin1[(rowbase + row) * 1024 + col] = f2bf(acc[mf][nfi][reg]);
            }
        }
    }
}

// ---------------- fc per slot, weighted ----------------
__global__ __launch_bounds__(256)
void fc_kernel(const float* __restrict__ fcw, const float* __restrict__ fcb,
               const float* __restrict__ h1f,
               const int* __restrict__ slot_b, const int* __restrict__ slot_k,
               const float* __restrict__ slot_w, const int* __restrict__ slot_e,
               float* __restrict__ wout)
{
    int s = blockIdx.x;
    int b = slot_b[s];
    if (b < 0) return;
    int tid = threadIdx.x;
    __shared__ float hv[HH];
    if (tid < HH) hv[tid] = h1f[(size_t)s * HH + tid];
    __syncthreads();
    int e = slot_e[s], kk = slot_k[s];
    float w = slot_w[s];
    for (int v = tid; v < VV; v += 256) {
        float sacc = fcb[e * VV + v];
        const float* fr = fcw + ((size_t)e * VV + v) * HH;
        #pragma unroll 4
        for (int d = 0; d < HH; d++) sacc += hv[d] * fr[d];
        wout[((size_t)b * 2 + kk) * VV + v] = w * sacc;
    }
}

__global__ void combine_kernel(const float* __restrict__ wout, float* __restrict__ out)
{
    int i = blockIdx.x * blockDim.x + threadIdx.x;
    if (i < BB * VV) {
        int b = i / VV, v = i % VV;
        out[i] = wout[((size_t)b * 2) * VV + v] + wout[((size_t)b * 2 + 1) * VV + v];
    }
}

extern "C" void kernel_launch(void* const* d_in, const int* in_sizes, int n_in,
                              void* d_out, int out_size, void* d_ws, size_t ws_size,
                              hipStream_t stream)
{
    const int*   x    = (const int*)d_in[0];
    const float* emb  = (const float*)d_in[1];
    const float* Wih0 = (const float*)d_in[2];
    const float* Whh0 = (const float*)d_in[3];
    const float* bih0 = (const float*)d_in[4];
    const float* bhh0 = (const float*)d_in[5];
    const float* Wih1 = (const float*)d_in[6];
    const float* Whh1 = (const float*)d_in[7];
    const float* bih1 = (const float*)d_in[8];
    const float* bhh1 = (const float*)d_in[9];
    const float* fcw  = (const float*)d_in[10];
    const float* fcb  = (const float*)d_in[11];
    const float* gw1  = (const float*)d_in[12];
    const float* gb1  = (const float*)d_in[13];
    const float* b1g  = (const float*)d_in[14];
    const float* b1b  = (const float*)d_in[15];
    const float* b1m  = (const float*)d_in[16];
    const float* b1v  = (const float*)d_in[17];
    const float* gw2  = (const float*)d_in[18];
    const float* gb2  = (const float*)d_in[19];
    const float* b2g  = (const float*)d_in[20];
    const float* b2b  = (const float*)d_in[21];
    const float* b2m  = (const float*)d_in[22];
    const float* b2v  = (const float*)d_in[23];
    const float* gw3  = (const float*)d_in[24];
    const float* gb3  = (const float*)d_in[25];

    const size_t NW = (size_t)EE * 8 * 64 * 512;  // ushorts per WR

    char* base = (char*)d_ws;
    size_t o = 0;
    auto alloc = [&](size_t bytes) { char* p = base + o; o = (o + bytes + 255) & ~(size_t)255; return p; };

    unsigned short* WR0  = (unsigned short*)alloc(NW * 2);
    unsigned short* WR1  = (unsigned short*)alloc(NW * 2);
    unsigned short* WG   = (unsigned short*)alloc(NW * 2);
    unsigned short* embW = (unsigned short*)alloc((size_t)EE * VV * FH * 2);
    float* bsum1 = (float*)alloc((size_t)EE * FH * 4);
    float* h1f   = (float*)alloc((size_t)SLOTS * HH * 4);
    float* wout  = (float*)alloc((size_t)BB * 2 * VV * 4);
    float* cst0  = (float*)alloc((size_t)NT * 512 * 8 * 4);
    float* cst1  = (float*)alloc((size_t)NT * 512 * 8 * 4);
    unsigned short* hsv0 = (unsigned short*)alloc((size_t)NT * 4096 * 2);
    unsigned short* hsv1 = (unsigned short*)alloc((size_t)NT * 4096 * 2);
    float* route_w = (float*)alloc((size_t)BB * 2 * 4);
    float* slot_w  = (float*)alloc((size_t)SLOTS * 4);
    int* route_i = (int*)alloc((size_t)BB * 2 * 4);
    int* slot_b  = (int*)alloc((size_t)SLOTS * 4);
    int* slot_k  = (int*)alloc((size_t)SLOTS * 4);
    int* slot_e  = (int*)alloc((size_t)SLOTS * 4);

    const size_t fixed_b = o;
    const size_t per_cc = (size_t)NT * 4096 * 2 + (size_t)NT * 16 * FH * 2;  // h0seq + zin1 per timestep
    int CC = 8;
    if (ws_size >= fixed_b + 80 * per_cc) CC = 80;
    else if (ws_size >= fixed_b + 16 * per_cc) CC = 16;

    unsigned short* h0seq = (unsigned short*)alloc((size_t)NT * CC * 4096 * 2);
    unsigned short* zin1  = (unsigned short*)alloc((size_t)NT * CC * 16 * FH * 2);

    prep_kernel<<<8192, 256, 0, stream>>>(Whh0, Wih1, Whh1, bih1, bhh1, WR0, WR1, WG, bsum1);
    embw_kernel<<<dim3(EE, 4), 256, 0, stream>>>(emb, Wih0, bih0, bhh0, embW);
    gating_kernel<<<BB, 128, 0, stream>>>(x, emb, gw1, gb1, b1g, b1b, b1m, b1v,
                                          gw2, gb2, b2g, b2b, b2m, b2v, gw3, gb3,
                                          route_i, route_w);
    route_kernel<<<1, 1024, 0, stream>>>(route_i, route_w, slot_b, slot_k, slot_w, slot_e);

    const int nchunks = TT / CC;
    for (int ch = 0; ch < nchunks; ch++) {
        int t0 = ch * CC;
        lstm_kernel<0><<<NT, 512, 0, stream>>>(t0, CC, WR0, embW, zin1, bsum1, x,
                                               slot_b, slot_e, h0seq, h1f, cst0, hsv0);
        gemm_zin<<<dim3(NT, CC / 8, 4), 256, 0, stream>>>(CC, h0seq, WG, slot_b, slot_e, zin1);
        lstm_kernel<1><<<NT, 512, 0, stream>>>(t0, CC, WR1, embW, zin1, bsum1, x,
                                               slot_b, slot_e, h0seq, h1f, cst1, hsv1);
    }

    fc_kernel<<<SLOTS, 256, 0, stream>>>(fcw, fcb, h1f, slot_b, slot_k, slot_w, slot_e, wout);
    combine_kernel<<<(BB * VV + 255) / 256, 256, 0, stream>>>(wout, (float*)d_out);
}

// Round 4
// 1572.127 us; speedup vs baseline: 3.9458x; 1.0419x over previous
//
#include <hip/hip_runtime.h>
#include <hip/hip_bf16.h>
#include <math.h>

#define BB 512
#define TT 80
#define VV 80
#define DD 128
#define HH 256
#define FH 1024
#define EE 8
#define GG1 512
#define GG2 256
#define MT 16
#define NT 72
#define SLOTS (NT*MT)   // 1152

typedef __attribute__((ext_vector_type(8))) short bf16x8;
typedef __attribute__((ext_vector_type(4))) float f32x4;

__device__ __forceinline__ float bf2f(unsigned short u) {
    unsigned int v = ((unsigned int)u) << 16;
    return __builtin_bit_cast(float, v);
}
__device__ __forceinline__ unsigned short f2bf(float f) {
    __hip_bfloat16 h = __float2bfloat16(f);
    return __builtin_bit_cast(unsigned short, h);
}
__device__ __forceinline__ float sigm(float x) { return 1.f / (1.f + __expf(-x)); }
__device__ __forceinline__ float tanh_f(float x) {
    float ax = fabsf(x);
    float r = 1.f - 2.f / (__expf(2.f * ax) + 1.f);
    return x < 0.f ? -r : r;
}

// ---------------- prep: pack Whh0/Whh1 (recurrent frag layout) + Wih1 (GEMM layout) ----------------
// WR: [e][w(8)][frag=kb*8+nf (64)][lane(64)][j(8)]
//     elem = W[gc][kk], gc=(nf>>1)*256 + w*32 + (nf&1)*16 + (l&15), kk=kb*32+(l>>4)*8+j
// WG: [e][nf(64)][kb(8)][lane(64)][j(8)]  elem = Wih1[gc=nf*16+(l&15)][kk=kb*32+(l>>4)*8+j]
__global__ void prep_kernel(const float* __restrict__ Whh0, const float* __restrict__ Wih1,
                            const float* __restrict__ Whh1,
                            const float* __restrict__ bih1, const float* __restrict__ bhh1,
                            unsigned short* __restrict__ WR0, unsigned short* __restrict__ WR1,
                            unsigned short* __restrict__ WG, float* __restrict__ bsum1)
{
    const int NW = EE * 8 * 64 * 512;  // 2097152
    const int ntot = 3 * NW + EE * FH;
    for (int idx = blockIdx.x * blockDim.x + threadIdx.x; idx < ntot;
         idx += gridDim.x * blockDim.x) {
        if (idx < 2 * NW) {
            int p = (idx >= NW) ? idx - NW : idx;
            const float* W = (idx >= NW) ? Whh1 : Whh0;
            int j = p & 7, l = (p >> 3) & 63, frag = (p >> 9) & 63, w = (p >> 15) & 7, e = p >> 18;
            int kb = frag >> 3, nf = frag & 7;
            int gc = (nf >> 1) * 256 + w * 32 + (nf & 1) * 16 + (l & 15);
            int kk = kb * 32 + (l >> 4) * 8 + j;
            unsigned short v = f2bf(W[((size_t)e * FH + gc) * HH + kk]);
            if (idx >= NW) WR1[p] = v; else WR0[p] = v;
        } else if (idx < 3 * NW) {
            int p = idx - 2 * NW;
            int j = p & 7, l = (p >> 3) & 63, kb = (p >> 9) & 7, nf = (p >> 12) & 63, e = p >> 18;
            int gc = nf * 16 + (l & 15);
            int kk = kb * 32 + (l >> 4) * 8 + j;
            WG[p] = f2bf(Wih1[((size_t)e * FH + gc) * HH + kk]);
        } else {
            int p = idx - 3 * NW;
            bsum1[p] = bih1[p] + bhh1[p];
        }
    }
}

// ---------------- embW[e][tok][1024] bf16 = emb[e,tok] @ Wih0^T + bih0 + bhh0 ----------------
__global__ __launch_bounds__(256)
void embw_kernel(const float* __restrict__ emb, const float* __restrict__ Wih0,
                 const float* __restrict__ bih0, const float* __restrict__ bhh0,
                 unsigned short* __restrict__ embW)
{
    const int e = blockIdx.x, ch = blockIdx.y;
    const int tid = threadIdx.x;
    const int gc = ch * 256 + tid;
    __shared__ float er[DD * VV];  // [d][tok]
    for (int i = tid; i < VV * DD; i += 256) {
        int tok = i >> 7, d = i & 127;
        er[d * VV + tok] = emb[((size_t)e * VV + tok) * DD + d];
    }
    __syncthreads();
    float acc[VV];
    #pragma unroll
    for (int v = 0; v < VV; v++) acc[v] = 0.f;
    const float* wr = Wih0 + ((size_t)e * FH + gc) * DD;
    for (int d = 0; d < DD; d++) {
        float wv = wr[d];
        #pragma unroll
        for (int v4 = 0; v4 < VV; v4 += 4) {
            float4 ev = *(const float4*)&er[d * VV + v4];
            acc[v4] += ev.x * wv; acc[v4 + 1] += ev.y * wv;
            acc[v4 + 2] += ev.z * wv; acc[v4 + 3] += ev.w * wv;
        }
    }
    float bias = bih0[e * FH + gc] + bhh0[e * FH + gc];
    #pragma unroll 4
    for (int v = 0; v < VV; v++)
        embW[((size_t)e * VV + v) * FH + gc] = f2bf(acc[v] + bias);
}

// ---------------- gating: feat -> MLP -> softmax -> top2 (fp32) ----------------
__global__ __launch_bounds__(128)
void gating_kernel(const int* __restrict__ x, const float* __restrict__ emb,
                   const float* __restrict__ gw1, const float* __restrict__ gb1,
                   const float* __restrict__ g1g, const float* __restrict__ g1b,
                   const float* __restrict__ g1m, const float* __restrict__ g1v,
                   const float* __restrict__ gw2, const float* __restrict__ gb2,
                   const float* __restrict__ g2g, const float* __restrict__ g2b,
                   const float* __restrict__ g2m, const float* __restrict__ g2v,
                   const float* __restrict__ gw3, const float* __restrict__ gb3,
                   int* __restrict__ route_i, float* __restrict__ route_w)
{
    int b = blockIdx.x, tid = threadIdx.x;
    __shared__ int tk[TT];
    __shared__ float feat[DD];
    __shared__ float h1[GG1];
    __shared__ float h2[GG2];
    __shared__ float lg[EE];
    if (tid < TT) tk[tid] = x[b * TT + tid];
    __syncthreads();
    if (tid < DD) {
        float s = 0.f;
        for (int t = 0; t < TT; t++) s += emb[(size_t)tk[t] * DD + tid];
        feat[tid] = s * (1.f / TT);
    }
    __syncthreads();
    for (int j = tid; j < GG1; j += 128) {
        float s = gb1[j];
        const float* wr = gw1 + (size_t)j * DD;
        for (int d = 0; d < DD; d++) s += feat[d] * wr[d];
        float y = (s - g1m[j]) / sqrtf(g1v[j] + 1e-5f) * g1g[j] + g1b[j];
        h1[j] = y > 0.f ? y : 0.f;
    }
    __syncthreads();
    for (int j = tid; j < GG2; j += 128) {
        float s = gb2[j];
        const float* wr = gw2 + (size_t)j * GG1;
        for (int d = 0; d < GG1; d++) s += h1[d] * wr[d];
        float y = (s - g2m[j]) / sqrtf(g2v[j] + 1e-5f) * g2g[j] + g2b[j];
        h2[j] = y > 0.f ? y : 0.f;
    }
    __syncthreads();
    if (tid < EE) {
        float s = gb3[tid];
        const float* wr = gw3 + (size_t)tid * GG2;
        for (int d = 0; d < GG2; d++) s += h2[d] * wr[d];
        lg[tid] = s;
    }
    __syncthreads();
    if (tid == 0) {
        int i0 = 0;
        for (int i = 1; i < EE; i++) if (lg[i] > lg[i0]) i0 = i;
        int i1 = (i0 == 0) ? 1 : 0;
        for (int i = 0; i < EE; i++) if (i != i0 && lg[i] > lg[i1]) i1 = i;
        float e1 = expf(lg[i1] - lg[i0]);
        float inv = 1.f / (1.f + e1);
        route_i[b * 2] = i0; route_i[b * 2 + 1] = i1;
        route_w[b * 2] = inv; route_w[b * 2 + 1] = e1 * inv;
    }
}

// ---------------- route: wave-ballot compaction, 16-padded per-expert regions ----------------
__global__ __launch_bounds__(1024)
void route_kernel(const int* __restrict__ route_i, const float* __restrict__ route_w,
                  int* __restrict__ slot_b, int* __restrict__ slot_k,
                  float* __restrict__ slot_w, int* __restrict__ slot_e)
{
    __shared__ int wcnt[16][EE];
    __shared__ int cnt[EE];
    __shared__ int off[EE + 1];
    int tid = threadIdx.x;
    int lane = tid & 63, wv = tid >> 6;
    int e = route_i[tid];
    unsigned long long below = (1ull << lane) - 1ull;
    int rankw = 0;
    #pragma unroll
    for (int q = 0; q < EE; q++) {
        unsigned long long m = __ballot(e == q);
        if (q == e) rankw = __popcll(m & below);
        if (lane == 0) wcnt[wv][q] = __popcll(m);
    }
    __syncthreads();
    if (tid < EE) {
        int c = 0;
        for (int w2 = 0; w2 < 16; w2++) c += wcnt[w2][tid];
        cnt[tid] = c;
    }
    __syncthreads();
    if (tid == 0) {
        off[0] = 0;
        for (int q = 0; q < EE; q++) off[q + 1] = off[q] + ((cnt[q] + MT - 1) / MT) * MT;
    }
    __syncthreads();
    for (int s = tid; s < SLOTS; s += 1024) {
        int e2 = 0;
        if (s < off[EE]) { for (int q = 0; q < EE; q++) if (s >= off[q]) e2 = q; }
        slot_b[s] = -1; slot_k[s] = 0; slot_w[s] = 0.f; slot_e[s] = e2;
    }
    __syncthreads();
    int rank = rankw;
    for (int w2 = 0; w2 < wv; w2++) rank += wcnt[w2][e];
    int s = off[e] + rank;
    slot_b[s] = tid >> 1; slot_k[s] = tid & 1; slot_w[s] = route_w[tid];
}

// ---------------- gather0: zin0[(tile,t)] = embW rows in C-frag layout ----------------
// frag layout per (tile,t): [gf(64)][lane(64)][reg(4)] ushort; value(row,col): row=(lane>>4)*4+reg, col=gf*16+(lane&15)
__global__ __launch_bounds__(256)
void gather0_kernel(int t0, int tcount, const int* __restrict__ x,
                    const unsigned short* __restrict__ embW,
                    const int* __restrict__ slot_b, const int* __restrict__ slot_e,
                    unsigned short* __restrict__ zin0)
{
    const int tile = blockIdx.x;
    if (slot_b[tile * MT] < 0) return;
    const int tl = blockIdx.y;
    const int tid = threadIdx.x;
    const int e = slot_e[tile * MT];
    __shared__ int toks[MT];
    if (tid < MT) {
        int b = slot_b[tile * MT + tid];
        toks[tid] = (b >= 0) ? x[b * TT + t0 + tl] : 0;
    }
    __syncthreads();
    unsigned short* out = zin0 + ((size_t)(tile * tcount + tl)) * 16384;
    #pragma unroll
    for (int k = 0; k < 16; k++) {
        int u = k * 256 + tid;          // (gf, lane)
        int gf = u >> 6, ln = u & 63;
        int col = gf * 16 + (ln & 15);
        int rb = (ln >> 4) * 4;
        ushort4 v;
        v.x = embW[((size_t)e * VV + toks[rb + 0]) * FH + col];
        v.y = embW[((size_t)e * VV + toks[rb + 1]) * FH + col];
        v.z = embW[((size_t)e * VV + toks[rb + 2]) * FH + col];
        v.w = embW[((size_t)e * VV + toks[rb + 3]) * FH + col];
        *(ushort4*)(out + (size_t)u * 4) = v;
    }
}

// ---------------- persistent LSTM chunk kernel: 1 block = 16 slots, full width ----------------
// 512 thr = 8 waves; wave w owns hcols [w*32, w*32+32) x 4 gates (nf = g*2+hc).
// h in LDS ping-pong (A-frag layout), c in registers, z-input arrives as C-frag init from zin.
// Weights: kb0-2 VGPR-resident (24 frags), kb3-7 streamed 2-deep from L2.
template<int LAYER>
__global__ __launch_bounds__(512, 2)
void lstm_kernel(int t0, int tcount,
                 const unsigned short* __restrict__ WR,
                 const unsigned short* __restrict__ zin,
                 const int* __restrict__ slot_b, const int* __restrict__ slot_e,
                 unsigned short* __restrict__ h0seq,
                 float* __restrict__ h1f,
                 float* __restrict__ cst, unsigned short* __restrict__ hsv)
{
    const int tile = blockIdx.x;
    if (slot_b[tile * MT] < 0) return;
    const int tid = threadIdx.x;
    const int lane = tid & 63;
    const int w = tid >> 6;
    const int e = slot_e[tile * MT];
    const int l15 = lane & 15;
    const int q = lane >> 4;

    __shared__ unsigned short hbuf[2][4096];   // A-frag layout [kb][lane][8]

    if (t0 == 0) {
        *(f32x4*)&hbuf[0][tid * 8] = (f32x4){0.f, 0.f, 0.f, 0.f};
    } else {
        *(bf16x8*)&hbuf[0][tid * 8] = *(const bf16x8*)(hsv + (size_t)tile * 4096 + tid * 8);
    }
    float c[8];
    if (t0 == 0) {
        #pragma unroll
        for (int i = 0; i < 8; i++) c[i] = 0.f;
    } else {
        f32x4 v0 = *(const f32x4*)&cst[((size_t)(tile * 512 + tid)) * 8];
        f32x4 v1 = *(const f32x4*)&cst[((size_t)(tile * 512 + tid)) * 8 + 4];
        c[0]=v0[0]; c[1]=v0[1]; c[2]=v0[2]; c[3]=v0[3];
        c[4]=v1[0]; c[5]=v1[1]; c[6]=v1[2]; c[7]=v1[3];
    }

    const unsigned short* WB = WR + ((size_t)(e * 8 + w) * 64) * 512 + lane * 8;
    bf16x8 wres[24];                 // kb 0..2 resident
    #pragma unroll
    for (int i = 0; i < 24; i++) wres[i] = *(const bf16x8*)(WB + (size_t)i * 512);

    const unsigned short* zbase = zin + ((size_t)tile * tcount) * 16384;
    int zoff[8];
    #pragma unroll
    for (int nf = 0; nf < 8; nf++) {
        int gf = (nf >> 1) * 16 + w * 2 + (nf & 1);
        zoff[nf] = (gf * 64 + lane) * 4;
    }

    // prefetch zin for t=0
    ushort4 zf[8];
    #pragma unroll
    for (int nf = 0; nf < 8; nf++) zf[nf] = *(const ushort4*)(zbase + zoff[nf]);

    __syncthreads();

    int cur = 0;
    for (int t = 0; t < tcount; t++) {
        // prefetch next step's zin (full step of latency to land)
        ushort4 zfn[8];
        {
            const unsigned short* zb = zbase + (size_t)((t + 1 < tcount) ? t + 1 : t) * 16384;
            #pragma unroll
            for (int nf = 0; nf < 8; nf++) zfn[nf] = *(const ushort4*)(zb + zoff[nf]);
        }
        // stream first two weight batches (kb3, kb4)
        bf16x8 w0[8], w1[8];
        #pragma unroll
        for (int nf = 0; nf < 8; nf++) w0[nf] = *(const bf16x8*)(WB + (size_t)(24 + nf) * 512);
        #pragma unroll
        for (int nf = 0; nf < 8; nf++) w1[nf] = *(const bf16x8*)(WB + (size_t)(32 + nf) * 512);

        // A fragments from h LDS (conflict-free: 16B/lane stride)
        bf16x8 a[8];
        #pragma unroll
        for (int kb = 0; kb < 8; kb++) a[kb] = *(const bf16x8*)&hbuf[cur][(kb * 64 + lane) * 8];

        // acc init = z input (C-frag)
        f32x4 acc[8];
        #pragma unroll
        for (int nf = 0; nf < 8; nf++) {
            acc[nf][0] = bf2f(zf[nf].x); acc[nf][1] = bf2f(zf[nf].y);
            acc[nf][2] = bf2f(zf[nf].z); acc[nf][3] = bf2f(zf[nf].w);
        }

        // resident MFMAs (kb 0..2)
        #pragma unroll
        for (int kb = 0; kb < 3; kb++)
            #pragma unroll
            for (int nf = 0; nf < 8; nf++)
                acc[nf] = __builtin_amdgcn_mfma_f32_16x16x32_bf16(a[kb], wres[kb * 8 + nf], acc[nf], 0, 0, 0);

        // streamed MFMAs kb3..7, 2-deep prefetch
        #pragma unroll
        for (int nf = 0; nf < 8; nf++)
            acc[nf] = __builtin_amdgcn_mfma_f32_16x16x32_bf16(a[3], w0[nf], acc[nf], 0, 0, 0);
        #pragma unroll
        for (int nf = 0; nf < 8; nf++) w0[nf] = *(const bf16x8*)(WB + (size_t)(40 + nf) * 512);
        #pragma unroll
        for (int nf = 0; nf < 8; nf++)
            acc[nf] = __builtin_amdgcn_mfma_f32_16x16x32_bf16(a[4], w1[nf], acc[nf], 0, 0, 0);
        #pragma unroll
        for (int nf = 0; nf < 8; nf++) w1[nf] = *(const bf16x8*)(WB + (size_t)(48 + nf) * 512);
        #pragma unroll
        for (int nf = 0; nf < 8; nf++)
            acc[nf] = __builtin_amdgcn_mfma_f32_16x16x32_bf16(a[5], w0[nf], acc[nf], 0, 0, 0);
        #pragma unroll
        for (int nf = 0; nf < 8; nf++) w0[nf] = *(const bf16x8*)(WB + (size_t)(56 + nf) * 512);
        #pragma unroll
        for (int nf = 0; nf < 8; nf++)
            acc[nf] = __builtin_amdgcn_mfma_f32_16x16x32_bf16(a[6], w1[nf], acc[nf], 0, 0, 0);
        #pragma unroll
        for (int nf = 0; nf < 8; nf++)
            acc[nf] = __builtin_amdgcn_mfma_f32_16x16x32_bf16(a[7], w0[nf], acc[nf], 0, 0, 0);

        // gate phase (all in registers)
        const int nxt = cur ^ 1;
        #pragma unroll
        for (int reg = 0; reg < 4; reg++) {
            int row = q * 4 + reg;
            #pragma unroll
            for (int hc = 0; hc < 2; hc++) {
                float iv = acc[0 + hc][reg];
                float fv = acc[2 + hc][reg];
                float gv = acc[4 + hc][reg];
                float ov = acc[6 + hc][reg];
                float cp = c[reg * 2 + hc];
                float cn = sigm(fv) * cp + sigm(iv) * tanh_f(gv);
                float hn = sigm(ov) * tanh_f(cn);
                c[reg * 2 + hc] = cn;
                int lane2 = row + ((hc * 2 + (l15 >> 3)) << 4);
                hbuf[nxt][((w << 6) + lane2) * 8 + (l15 & 7)] = f2bf(hn);
                if (LAYER == 1 && t0 + t == TT - 1)
                    h1f[((size_t)(tile * MT + row)) * HH + w * 32 + hc * 16 + l15] = hn;
            }
        }
        __syncthreads();
        cur = nxt;
        #pragma unroll
        for (int nf = 0; nf < 8; nf++) zf[nf] = zfn[nf];
        if (LAYER == 0) {
            *(bf16x8*)(h0seq + ((size_t)(tile * tcount + t)) * 4096 + tid * 8) =
                *(const bf16x8*)&hbuf[cur][tid * 8];
        }
    }

    // save chunk state
    f32x4 v0, v1;
    v0[0]=c[0]; v0[1]=c[1]; v0[2]=c[2]; v0[3]=c[3];
    v1[0]=c[4]; v1[1]=c[5]; v1[2]=c[6]; v1[3]=c[7];
    *(f32x4*)&cst[((size_t)(tile * 512 + tid)) * 8] = v0;
    *(f32x4*)&cst[((size_t)(tile * 512 + tid)) * 8 + 4] = v1;
    *(bf16x8*)(hsv + (size_t)tile * 4096 + tid * 8) = *(const bf16x8*)&hbuf[cur][tid * 8];
}

// ---------------- zin1[(tile,t)] = h0seq @ Wih1^T + bsum1, C-frag layout ----------------
__global__ __launch_bounds__(256, 2)
void gemm_zin(int tcount,
              const unsigned short* __restrict__ h0seq,
              const unsigned short* __restrict__ WG,
              const float* __restrict__ bsum1,
              const int* __restrict__ slot_b, const int* __restrict__ slot_e,
              unsigned short* __restrict__ zin1)
{
    const int tile = blockIdx.x;
    if (slot_b[tile * MT] < 0) return;
    const int tch = blockIdx.y, nch = blockIdx.z;
    const int tid = threadIdx.x, lane = tid & 63, w = tid >> 6;
    const int e = slot_e[tile * MT];
    __shared__ unsigned short Abuf[32768];  // 8 tloc x A-frag layout
    const unsigned short* Asrc = h0seq + ((size_t)(tile * tcount + tch * 8)) * 4096;
    #pragma unroll
    for (int i = 0; i < 16; i++) {
        int o = (i * 256 + tid) * 8;
        *(bf16x8*)&Abuf[o] = *(const bf16x8*)&Asrc[o];
    }
    __syncthreads();
    const unsigned short* Bp = WG + ((size_t)(e * 64 + nch * 16 + w * 4)) * 4096 + lane * 8;
    f32x4 acc[8][4];
    #pragma unroll
    for (int mf = 0; mf < 8; mf++)
        #pragma unroll
        for (int nfi = 0; nfi < 4; nfi++) acc[mf][nfi] = (f32x4){0.f, 0.f, 0.f, 0.f};
    #pragma unroll
    for (int kb = 0; kb < 8; kb++) {
        bf16x8 b0 = *(const bf16x8*)(Bp + 0 * 4096 + kb * 512);
        bf16x8 b1 = *(const bf16x8*)(Bp + 1 * 4096 + kb * 512);
        bf16x8 b2 = *(const bf16x8*)(Bp + 2 * 4096 + kb * 512);
        bf16x8 b3 = *(const bf16x8*)(Bp + 3 * 4096 + kb * 512);
        #pragma unroll
        for (int mf = 0; mf < 8; mf++) {
            bf16x8 a = *(const bf16x8*)&Abuf[(mf * 8 + kb) * 512 + lane * 8];
            acc[mf][0] = __builtin_amdgcn_mfma_f32_16x16x32_bf16(a, b0, acc[mf][0], 0, 0, 0);
            acc[mf][1] = __builtin_amdgcn_mfma_f32_16x16x32_bf16(a, b1, acc[mf][1], 0, 0, 0);
            acc[mf][2] = __builtin_amdgcn_mfma_f32_16x16x32_bf16(a, b2, acc[mf][2], 0, 0, 0);
            acc[mf][3] = __builtin_amdgcn_mfma_f32_16x16x32_bf16(a, b3, acc[mf][3], 0, 0, 0);
        }
    }
    const int l15 = lane & 15;
    #pragma unroll
    for (int mf = 0; mf < 8; mf++) {
        unsigned short* ob = zin1 + ((size_t)(tile * tcount + tch * 8 + mf)) * 16384;
        #pragma unroll
        for (int nfi = 0; nfi < 4; nfi++) {
            int gf = nch * 16 + w * 4 + nfi;
            float bs = bsum1[e * FH + gf * 16 + l15];
            ushort4 v;
            v.x = f2bf(acc[mf][nfi][0] + bs);
            v.y = f2bf(acc[mf][nfi][1] + bs);
            v.z = f2bf(acc[mf][nfi][2] + bs);
            v.w = f2bf(acc[mf][nfi][3] + bs);
            *(ushort4*)(ob + (size_t)(gf * 64 + lane) * 4) = v;
        }
    }
}

// ---------------- fc per slot, weighted ----------------
__global__ __launch_bounds__(256)
void fc_kernel(const float* __restrict__ fcw, const float* __restrict__ fcb,
               const float* __restrict__ h1f,
               const int* __restrict__ slot_b, const int* __restrict__ slot_k,
               const float* __restrict__ slot_w, const int* __restrict__ slot_e,
               float* __restrict__ wout)
{
    int s = blockIdx.x;
    int b = slot_b[s];
    if (b < 0) return;
    int tid = threadIdx.x;
    __shared__ float hv[HH];
    if (tid < HH) hv[tid] = h1f[(size_t)s * HH + tid];
    __syncthreads();
    int e = slot_e[s], kk = slot_k[s];
    float w = slot_w[s];
    for (int v = tid; v < VV; v += 256) {
        float sacc = fcb[e * VV + v];
        const float* fr = fcw + ((size_t)e * VV + v) * HH;
        #pragma unroll 4
        for (int d = 0; d < HH; d++) sacc += hv[d] * fr[d];
        wout[((size_t)b * 2 + kk) * VV + v] = w * sacc;
    }
}

__global__ void combine_kernel(const float* __restrict__ wout, float* __restrict__ out)
{
    int i = blockIdx.x * blockDim.x + threadIdx.x;
    if (i < BB * VV) {
        int b = i / VV, v = i % VV;
        out[i] = wout[((size_t)b * 2) * VV + v] + wout[((size_t)b * 2 + 1) * VV + v];
    }
}

extern "C" void kernel_launch(void* const* d_in, const int* in_sizes, int n_in,
                              void* d_out, int out_size, void* d_ws, size_t ws_size,
                              hipStream_t stream)
{
    const int*   x    = (const int*)d_in[0];
    const float* emb  = (const float*)d_in[1];
    const float* Wih0 = (const float*)d_in[2];
    const float* Whh0 = (const float*)d_in[3];
    const float* bih0 = (const float*)d_in[4];
    const float* bhh0 = (const float*)d_in[5];
    const float* Wih1 = (const float*)d_in[6];
    const float* Whh1 = (const float*)d_in[7];
    const float* bih1 = (const float*)d_in[8];
    const float* bhh1 = (const float*)d_in[9];
    const float* fcw  = (const float*)d_in[10];
    const float* fcb  = (const float*)d_in[11];
    const float* gw1  = (const float*)d_in[12];
    const float* gb1  = (const float*)d_in[13];
    const float* b1g  = (const float*)d_in[14];
    const float* b1b  = (const float*)d_in[15];
    const float* b1m  = (const float*)d_in[16];
    const float* b1v  = (const float*)d_in[17];
    const float* gw2  = (const float*)d_in[18];
    const float* gb2  = (const float*)d_in[19];
    const float* b2g  = (const float*)d_in[20];
    const float* b2b  = (const float*)d_in[21];
    const float* b2m  = (const float*)d_in[22];
    const float* b2v  = (const float*)d_in[23];
    const float* gw3  = (const float*)d_in[24];
    const float* gb3  = (const float*)d_in[25];

    const size_t NW = (size_t)EE * 8 * 64 * 512;  // ushorts per WR

    char* base = (char*)d_ws;
    size_t o = 0;
    auto alloc = [&](size_t bytes) { char* p = base + o; o = (o + bytes + 255) & ~(size_t)255; return p; };

    unsigned short* WR0  = (unsigned short*)alloc(NW * 2);
    unsigned short* WR1  = (unsigned short*)alloc(NW * 2);
    unsigned short* WG   = (unsigned short*)alloc(NW * 2);
    unsigned short* embW = (unsigned short*)alloc((size_t)EE * VV * FH * 2);
    float* bsum1 = (float*)alloc((size_t)EE * FH * 4);
    float* h1f   = (float*)alloc((size_t)SLOTS * HH * 4);
    float* wout  = (float*)alloc((size_t)BB * 2 * VV * 4);
    float* cst0  = (float*)alloc((size_t)NT * 512 * 8 * 4);
    float* cst1  = (float*)alloc((size_t)NT * 512 * 8 * 4);
    unsigned short* hsv0 = (unsigned short*)alloc((size_t)NT * 4096 * 2);
    unsigned short* hsv1 = (unsigned short*)alloc((size_t)NT * 4096 * 2);
    float* route_w = (float*)alloc((size_t)BB * 2 * 4);
    float* slot_w  = (float*)alloc((size_t)SLOTS * 4);
    int* route_i = (int*)alloc((size_t)BB * 2 * 4);
    int* slot_b  = (int*)alloc((size_t)SLOTS * 4);
    int* slot_k  = (int*)alloc((size_t)SLOTS * 4);
    int* slot_e  = (int*)alloc((size_t)SLOTS * 4);

    const size_t fixed_b = o;
    // per-timestep: h0seq (NT*4096*2) + zin0 (NT*16384*2) + zin1 (NT*16384*2)
    const size_t per_cc = (size_t)NT * 4096 * 2 + 2 * (size_t)NT * 16384 * 2;
    int CC = 8;
    if (ws_size >= fixed_b + 80 * per_cc + 1024) CC = 80;
    else if (ws_size >= fixed_b + 40 * per_cc + 1024) CC = 40;
    else if (ws_size >= fixed_b + 16 * per_cc + 1024) CC = 16;

    unsigned short* h0seq = (unsigned short*)alloc((size_t)NT * CC * 4096 * 2);
    unsigned short* zin0  = (unsigned short*)alloc((size_t)NT * CC * 16384 * 2);
    unsigned short* zin1  = (unsigned short*)alloc((size_t)NT * CC * 16384 * 2);

    prep_kernel<<<8192, 256, 0, stream>>>(Whh0, Wih1, Whh1, bih1, bhh1, WR0, WR1, WG, bsum1);
    embw_kernel<<<dim3(EE, 4), 256, 0, stream>>>(emb, Wih0, bih0, bhh0, embW);
    gating_kernel<<<BB, 128, 0, stream>>>(x, emb, gw1, gb1, b1g, b1b, b1m, b1v,
                                          gw2, gb2, b2g, b2b, b2m, b2v, gw3, gb3,
                                          route_i, route_w);
    route_kernel<<<1, 1024, 0, stream>>>(route_i, route_w, slot_b, slot_k, slot_w, slot_e);

    const int nchunks = TT / CC;
    for (int ch = 0; ch < nchunks; ch++) {
        int t0 = ch * CC;
        gather0_kernel<<<dim3(NT, CC), 256, 0, stream>>>(t0, CC, x, embW, slot_b, slot_e, zin0);
        lstm_kernel<0><<<NT, 512, 0, stream>>>(t0, CC, WR0, zin0, slot_b, slot_e,
                                               h0seq, h1f, cst0, hsv0);
        gemm_zin<<<dim3(NT, CC / 8, 4), 256, 0, stream>>>(CC, h0seq, WG, bsum1,
                                                          slot_b, slot_e, zin1);
        lstm_kernel<1><<<NT, 512, 0, stream>>>(t0, CC, WR1, zin1, slot_b, slot_e,
                                               h0seq, h1f, cst1, hsv1);
    }

    fc_kernel<<<SLOTS, 256, 0, stream>>>(fcw, fcb, h1f, slot_b, slot_k, slot_w, slot_e, wout);
    combine_kernel<<<(BB * VV + 255) / 256, 256, 0, stream>>>(wout, (float*)d_out);
}

// Round 5
// 1217.043 us; speedup vs baseline: 5.0970x; 1.2918x over previous
//
#include <hip/hip_runtime.h>
#include <hip/hip_bf16.h>
#include <math.h>

#define BB 512
#define TT 80
#define VV 80
#define DD 128
#define HH 256
#define FH 1024
#define EE 8
#define GG1 512
#define GG2 256
#define MT 16
#define NT 72
#define SLOTS (NT*MT)   // 1152

typedef __attribute__((ext_vector_type(8))) short bf16x8;
typedef __attribute__((ext_vector_type(4))) float f32x4;

#define SCOPE_AGENT __HIP_MEMORY_SCOPE_AGENT

__device__ __forceinline__ float bf2f(unsigned short u) {
    unsigned int v = ((unsigned int)u) << 16;
    return __builtin_bit_cast(float, v);
}
__device__ __forceinline__ unsigned short f2bf(float f) {
    __hip_bfloat16 h = __float2bfloat16(f);
    return __builtin_bit_cast(unsigned short, h);
}
__device__ __forceinline__ float sigm(float x) { return 1.f / (1.f + __expf(-x)); }
__device__ __forceinline__ float tanh_f(float x) {
    float ax = fabsf(x);
    float r = 1.f - 2.f / (__expf(2.f * ax) + 1.f);
    return x < 0.f ? -r : r;
}

// ---------------- prep (vectorized b128): pack recurrent weights + Wih1 + bias sums ----------------
// WR: [e][half(2)][w(8)][kb(8)][g(4)][lane(64)][j(8)]
//     elem = W[gc][kk]; gc = g*256 + half*128 + w*16 + (l&15); kk = kb*32 + (l>>4)*8 + j
// WG: [e][gf(64)][kb(8)][lane(64)][j(8)]  elem = Wih1[gf*16+(l&15)][kb*32+(l>>4)*8+j]
__global__ void prep_kernel(const float* __restrict__ Whh0, const float* __restrict__ Wih1,
                            const float* __restrict__ Whh1,
                            const float* __restrict__ bih1, const float* __restrict__ bhh1,
                            unsigned short* __restrict__ WR0, unsigned short* __restrict__ WR1,
                            unsigned short* __restrict__ WG, float* __restrict__ bsum1)
{
    const int NB = 262144;                 // entry groups of 8 per array
    const int ntot = 3 * NB + EE * FH;
    for (int idx = blockIdx.x * blockDim.x + threadIdx.x; idx < ntot;
         idx += gridDim.x * blockDim.x) {
        if (idx < 3 * NB) {
            int arr = idx / NB;
            int p = idx - arr * NB;
            int gc, kk, e;
            const float* src;
            if (arr < 2) {
                int l = p & 63, g = (p >> 6) & 3, kb = (p >> 8) & 7;
                int w = (p >> 11) & 7, half = (p >> 14) & 1; e = (p >> 15) & 7;
                gc = g * 256 + half * 128 + w * 16 + (l & 15);
                kk = kb * 32 + ((l >> 4) * 8);
                src = (arr == 0) ? Whh0 : Whh1;
            } else {
                int l = p & 63, kb = (p >> 6) & 7, gf = (p >> 9) & 63; e = (p >> 15) & 7;
                gc = gf * 16 + (l & 15);
                kk = kb * 32 + ((l >> 4) * 8);
                src = Wih1;
            }
            const float* sp = src + ((size_t)e * FH + gc) * HH + kk;
            float4 f0 = *(const float4*)sp;
            float4 f1 = *(const float4*)(sp + 4);
            unsigned short out[8];
            out[0] = f2bf(f0.x); out[1] = f2bf(f0.y); out[2] = f2bf(f0.z); out[3] = f2bf(f0.w);
            out[4] = f2bf(f1.x); out[5] = f2bf(f1.y); out[6] = f2bf(f1.z); out[7] = f2bf(f1.w);
            unsigned short* dst = (arr == 0 ? WR0 : arr == 1 ? WR1 : WG) + (size_t)p * 8;
            *(uint4*)dst = *(uint4*)out;
        } else {
            int p = idx - 3 * NB;
            bsum1[p] = bih1[p] + bhh1[p];
        }
    }
}

// ---------------- embT[e][tok][col(256)][g(4)] bf16 = emb[e,tok] @ Wih0^T + bih0 + bhh0 ----------------
__global__ __launch_bounds__(256)
void embw_kernel(const float* __restrict__ emb, const float* __restrict__ Wih0,
                 const float* __restrict__ bih0, const float* __restrict__ bhh0,
                 unsigned short* __restrict__ embT)
{
    const int e = blockIdx.x, g = blockIdx.y;
    const int tid = threadIdx.x;           // col
    const int gc = g * 256 + tid;
    __shared__ float er[DD * VV];  // [d][tok]
    for (int i = tid; i < VV * DD; i += 256) {
        int tok = i >> 7, d = i & 127;
        er[d * VV + tok] = emb[((size_t)e * VV + tok) * DD + d];
    }
    __syncthreads();
    float acc[VV];
    #pragma unroll
    for (int v = 0; v < VV; v++) acc[v] = 0.f;
    const float* wr = Wih0 + ((size_t)e * FH + gc) * DD;
    for (int d = 0; d < DD; d++) {
        float wv = wr[d];
        #pragma unroll
        for (int v4 = 0; v4 < VV; v4 += 4) {
            float4 ev = *(const float4*)&er[d * VV + v4];
            acc[v4] += ev.x * wv; acc[v4 + 1] += ev.y * wv;
            acc[v4 + 2] += ev.z * wv; acc[v4 + 3] += ev.w * wv;
        }
    }
    float bias = bih0[e * FH + gc] + bhh0[e * FH + gc];
    #pragma unroll 4
    for (int v = 0; v < VV; v++)
        embT[(((size_t)e * VV + v) * 256 + tid) * 4 + g] = f2bf(acc[v] + bias);
}

// ---------------- gating: feat -> MLP -> softmax -> top2 (fp32) ----------------
__global__ __launch_bounds__(128)
void gating_kernel(const int* __restrict__ x, const float* __restrict__ emb,
                   const float* __restrict__ gw1, const float* __restrict__ gb1,
                   const float* __restrict__ g1g, const float* __restrict__ g1b,
                   const float* __restrict__ g1m, const float* __restrict__ g1v,
                   const float* __restrict__ gw2, const float* __restrict__ gb2,
                   const float* __restrict__ g2g, const float* __restrict__ g2b,
                   const float* __restrict__ g2m, const float* __restrict__ g2v,
                   const float* __restrict__ gw3, const float* __restrict__ gb3,
                   int* __restrict__ route_i, float* __restrict__ route_w)
{
    int b = blockIdx.x, tid = threadIdx.x;
    __shared__ int tk[TT];
    __shared__ float feat[DD];
    __shared__ float h1[GG1];
    __shared__ float h2[GG2];
    __shared__ float lg[EE];
    if (tid < TT) tk[tid] = x[b * TT + tid];
    __syncthreads();
    if (tid < DD) {
        float s = 0.f;
        for (int t = 0; t < TT; t++) s += emb[(size_t)tk[t] * DD + tid];
        feat[tid] = s * (1.f / TT);
    }
    __syncthreads();
    for (int j = tid; j < GG1; j += 128) {
        float s = gb1[j];
        const float* wr = gw1 + (size_t)j * DD;
        for (int d = 0; d < DD; d++) s += feat[d] * wr[d];
        float y = (s - g1m[j]) / sqrtf(g1v[j] + 1e-5f) * g1g[j] + g1b[j];
        h1[j] = y > 0.f ? y : 0.f;
    }
    __syncthreads();
    for (int j = tid; j < GG2; j += 128) {
        float s = gb2[j];
        const float* wr = gw2 + (size_t)j * GG1;
        for (int d = 0; d < GG1; d++) s += h1[d] * wr[d];
        float y = (s - g2m[j]) / sqrtf(g2v[j] + 1e-5f) * g2g[j] + g2b[j];
        h2[j] = y > 0.f ? y : 0.f;
    }
    __syncthreads();
    if (tid < EE) {
        float s = gb3[tid];
        const float* wr = gw3 + (size_t)tid * GG2;
        for (int d = 0; d < GG2; d++) s += h2[d] * wr[d];
        lg[tid] = s;
    }
    __syncthreads();
    if (tid == 0) {
        int i0 = 0;
        for (int i = 1; i < EE; i++) if (lg[i] > lg[i0]) i0 = i;
        int i1 = (i0 == 0) ? 1 : 0;
        for (int i = 0; i < EE; i++) if (i != i0 && lg[i] > lg[i1]) i1 = i;
        float e1 = expf(lg[i1] - lg[i0]);
        float inv = 1.f / (1.f + e1);
        route_i[b * 2] = i0; route_i[b * 2 + 1] = i1;
        route_w[b * 2] = inv; route_w[b * 2 + 1] = e1 * inv;
    }
}

// ---------------- route: wave-ballot compaction, 16-padded per-expert regions ----------------
__global__ __launch_bounds__(1024)
void route_kernel(const int* __restrict__ route_i, const float* __restrict__ route_w,
                  int* __restrict__ slot_b, int* __restrict__ slot_k,
                  float* __restrict__ slot_w, int* __restrict__ slot_e)
{
    __shared__ int wcnt[16][EE];
    __shared__ int cnt[EE];
    __shared__ int off[EE + 1];
    int tid = threadIdx.x;
    int lane = tid & 63, wv = tid >> 6;
    int e = route_i[tid];
    unsigned long long below = (1ull << lane) - 1ull;
    int rankw = 0;
    #pragma unroll
    for (int q = 0; q < EE; q++) {
        unsigned long long m = __ballot(e == q);
        if (q == e) rankw = __popcll(m & below);
        if (lane == 0) wcnt[wv][q] = __popcll(m);
    }
    __syncthreads();
    if (tid < EE) {
        int c = 0;
        for (int w2 = 0; w2 < 16; w2++) c += wcnt[w2][tid];
        cnt[tid] = c;
    }
    __syncthreads();
    if (tid == 0) {
        off[0] = 0;
        for (int q = 0; q < EE; q++) off[q + 1] = off[q] + ((cnt[q] + MT - 1) / MT) * MT;
    }
    __syncthreads();
    for (int s = tid; s < SLOTS; s += 1024) {
        int e2 = 0;
        if (s < off[EE]) { for (int q = 0; q < EE; q++) if (s >= off[q]) e2 = q; }
        slot_b[s] = -1; slot_k[s] = 0; slot_w[s] = 0.f; slot_e[s] = e2;
    }
    __syncthreads();
    int rank = rankw;
    for (int w2 = 0; w2 < wv; w2++) rank += wcnt[w2][e];
    int s = off[e] + rank;
    slot_b[s] = tid >> 1; slot_k[s] = tid & 1; slot_w[s] = route_w[tid];
}

// ---------------- paired half-tile persistent LSTM: block = 16 slots x 128 hidden cols ----------------
// grid = NT*2; pair (tile,0)/(tile,1) exchange h halves per step via agent-scope atomics.
// 512 thr = 8 waves; wave w owns hcols [half*128 + w*16, +16) x 4 gates. All weights VGPR-resident.
template<int LAYER>
__global__ __launch_bounds__(512, 2)
void lstm_kernel(int t0, int tcount,
                 const unsigned short* __restrict__ WR,
                 const unsigned short* __restrict__ embT,
                 const unsigned short* __restrict__ zin1,
                 const int* __restrict__ x,
                 const int* __restrict__ slot_b, const int* __restrict__ slot_e,
                 unsigned short* __restrict__ h0seq,
                 float* __restrict__ h1f,
                 float* __restrict__ cst, unsigned short* __restrict__ hsv,
                 unsigned int* hx, int* flags)
{
    const int tile = blockIdx.x >> 1;
    const int half = blockIdx.x & 1;
    if (slot_b[tile * MT] < 0) return;
    const int tid = threadIdx.x;
    const int lane = tid & 63;
    const int w = tid >> 6;
    const int e = slot_e[tile * MT];
    const int l15 = lane & 15;
    const int q = lane >> 4;
    const int hcb = half * 128 + w * 16;        // wave's hidden-col base
    const int col = hcb + l15;                  // this lane's hidden col
    const int abskb_own = col >> 5;
    const int sc_base = ((abskb_own * 64 + 16 * ((col >> 3) & 3)) << 3) + (col & 7);

    __shared__ unsigned short hbuf[2][4096];    // A-frag layout [kb(8)][lane(64)][j(8)]
    __shared__ int toks[TT * 16];

    int* flag_me = flags + (tile * 2 + half);
    int* flag_p  = flags + (tile * 2 + (half ^ 1));

    if (LAYER == 0) {
        for (int i = tid; i < tcount * 16; i += 512)
            toks[i] = x[max(slot_b[tile * MT + (i & 15)], 0) * TT + t0 + (i >> 4)];
    }

    if (t0 == 0) {
        *(f32x4*)&hbuf[0][tid * 8] = (f32x4){0.f, 0.f, 0.f, 0.f};
    } else {
        *(bf16x8*)&hbuf[0][tid * 8] = *(const bf16x8*)(hsv + (size_t)tile * 4096 + tid * 8);
    }
    float c[4];
    if (t0 == 0) {
        c[0] = c[1] = c[2] = c[3] = 0.f;
    } else {
        f32x4 cv = *(const f32x4*)&cst[((size_t)(tile * 2 + half) * 512 + tid) * 4];
        c[0] = cv[0]; c[1] = cv[1]; c[2] = cv[2]; c[3] = cv[3];
    }

    // resident weights: 32 frags = 128 VGPRs
    const unsigned short* WB = WR + (((size_t)(e * 2 + half) * 8 + w) * 32) * 512 + (size_t)lane * 8;
    bf16x8 wres[32];
    #pragma unroll
    for (int i = 0; i < 32; i++) wres[i] = *(const bf16x8*)(WB + (size_t)i * 512);

    __syncthreads();

    // z prefetch for t = 0
    ushort4 zf[4];
    if (LAYER == 0) {
        #pragma unroll
        for (int reg = 0; reg < 4; reg++) {
            int tok = toks[(q * 4 + reg)];
            zf[reg] = *(const ushort4*)(embT + (((size_t)(e * VV + tok)) * 256 + col) * 4);
        }
    } else {
        #pragma unroll
        for (int g = 0; g < 4; g++) {
            int gf = g * 16 + half * 8 + w;
            zf[g] = *(const ushort4*)(zin1 + ((size_t)tile * tcount) * 16384 + (gf * 64 + lane) * 4);
        }
    }

    int cur = 0;
    for (int t = 0; t < tcount; t++) {
        // prefetch next step's z
        ushort4 zfn[4];
        {
            int tn = (t + 1 < tcount) ? t + 1 : t;
            if (LAYER == 0) {
                #pragma unroll
                for (int reg = 0; reg < 4; reg++) {
                    int tok = toks[tn * 16 + q * 4 + reg];
                    zfn[reg] = *(const ushort4*)(embT + (((size_t)(e * VV + tok)) * 256 + col) * 4);
                }
            } else {
                #pragma unroll
                for (int g = 0; g < 4; g++) {
                    int gf = g * 16 + half * 8 + w;
                    zfn[g] = *(const ushort4*)(zin1 + ((size_t)(tile * tcount + tn)) * 16384 + (gf * 64 + lane) * 4);
                }
            }
        }

        // import partner h_{t-1}
        if (t > 0 && tid < 256) {
            const int target = t0 + t;
            while (__hip_atomic_load(flag_p, __ATOMIC_RELAXED, SCOPE_AGENT) < target)
                __builtin_amdgcn_s_sleep(1);
            int kbi = tid >> 6, l = tid & 63;
            unsigned int* s = hx + ((((size_t)(tile * 2 + (half ^ 1)) * 2 + ((t - 1) & 1)) * 4 + kbi) * 64 + l) * 4;
            uint4 v;
            v.x = __hip_atomic_load(s + 0, __ATOMIC_RELAXED, SCOPE_AGENT);
            v.y = __hip_atomic_load(s + 1, __ATOMIC_RELAXED, SCOPE_AGENT);
            v.z = __hip_atomic_load(s + 2, __ATOMIC_RELAXED, SCOPE_AGENT);
            v.w = __hip_atomic_load(s + 3, __ATOMIC_RELAXED, SCOPE_AGENT);
            int pkb = (half ^ 1) * 4 + kbi;
            *(uint4*)&hbuf[cur][(pkb * 64 + l) * 8] = v;
        }
        __syncthreads();   // (A) hbuf[cur] complete

        bf16x8 a[8];
        #pragma unroll
        for (int kb = 0; kb < 8; kb++) a[kb] = *(const bf16x8*)&hbuf[cur][(kb * 64 + lane) * 8];

        f32x4 acc[4];
        if (LAYER == 0) {
            #pragma unroll
            for (int g = 0; g < 4; g++) {
                acc[g][0] = bf2f(((const unsigned short*)&zf[0])[g]);
                acc[g][1] = bf2f(((const unsigned short*)&zf[1])[g]);
                acc[g][2] = bf2f(((const unsigned short*)&zf[2])[g]);
                acc[g][3] = bf2f(((const unsigned short*)&zf[3])[g]);
            }
        } else {
            #pragma unroll
            for (int g = 0; g < 4; g++) {
                acc[g][0] = bf2f(zf[g].x); acc[g][1] = bf2f(zf[g].y);
                acc[g][2] = bf2f(zf[g].z); acc[g][3] = bf2f(zf[g].w);
            }
        }

        #pragma unroll
        for (int kb = 0; kb < 8; kb++)
            #pragma unroll
            for (int g = 0; g < 4; g++)
                acc[g] = __builtin_amdgcn_mfma_f32_16x16x32_bf16(a[kb], wres[kb * 4 + g], acc[g], 0, 0, 0);

        // gate phase: lane owns 4 rows x 1 col
        const int nxt = cur ^ 1;
        #pragma unroll
        for (int reg = 0; reg < 4; reg++) {
            float iv = acc[0][reg], fv = acc[1][reg], gv = acc[2][reg], ov = acc[3][reg];
            float cn = sigm(fv) * c[reg] + sigm(iv) * tanh_f(gv);
            float hn = sigm(ov) * tanh_f(cn);
            c[reg] = cn;
            int r = q * 4 + reg;
            hbuf[nxt][sc_base + r * 8] = f2bf(hn);
            if (LAYER == 1 && t0 + t == TT - 1)
                h1f[((size_t)(tile * MT + r)) * HH + col] = hn;
        }
        __syncthreads();   // (B) own half of hbuf[nxt] ready

        const bool doX = (t + 1 < tcount);
        if (tid < 256) {
            int kbi = tid >> 6, l = tid & 63;
            int abskb = half * 4 + kbi;
            uint4 v = *(const uint4*)&hbuf[nxt][(abskb * 64 + l) * 8];
            if (LAYER == 0)
                *(uint4*)(h0seq + ((size_t)(tile * tcount + t)) * 4096 + (abskb * 64 + l) * 8) = v;
            if (doX) {
                unsigned int* d = hx + ((((size_t)(tile * 2 + half) * 2 + (t & 1)) * 4 + kbi) * 64 + l) * 4;
                __hip_atomic_store(d + 0, v.x, __ATOMIC_RELAXED, SCOPE_AGENT);
                __hip_atomic_store(d + 1, v.y, __ATOMIC_RELAXED, SCOPE_AGENT);
                __hip_atomic_store(d + 2, v.z, __ATOMIC_RELAXED, SCOPE_AGENT);
                __hip_atomic_store(d + 3, v.w, __ATOMIC_RELAXED, SCOPE_AGENT);
            }
        }
        if (doX) {
            asm volatile("s_waitcnt vmcnt(0)" ::: "memory");
            __syncthreads();   // (C) all exports drained
            if (tid == 0)
                __hip_atomic_store(flag_me, t0 + t + 1, __ATOMIC_RELEASE, SCOPE_AGENT);
        }
        cur = nxt;
        zf[0] = zfn[0]; zf[1] = zfn[1]; zf[2] = zfn[2]; zf[3] = zfn[3];
    }

    // save chunk state (own regions)
    f32x4 cv; cv[0] = c[0]; cv[1] = c[1]; cv[2] = c[2]; cv[3] = c[3];
    *(f32x4*)&cst[((size_t)(tile * 2 + half) * 512 + tid) * 4] = cv;
    if (tid < 256) {
        int kbi = tid >> 6, l = tid & 63;
        int abskb = half * 4 + kbi;
        *(uint4*)(hsv + (size_t)tile * 4096 + (abskb * 64 + l) * 8) =
            *(const uint4*)&hbuf[cur][(abskb * 64 + l) * 8];
    }
}

// ---------------- zin1[(tile,t)] = h0seq @ Wih1^T + bsum1, C-frag layout ----------------
__global__ __launch_bounds__(256, 2)
void gemm_zin(int tcount,
              const unsigned short* __restrict__ h0seq,
              const unsigned short* __restrict__ WG,
              const float* __restrict__ bsum1,
              const int* __restrict__ slot_b, const int* __restrict__ slot_e,
              unsigned short* __restrict__ zin1)
{
    const int tile = blockIdx.x;
    if (slot_b[tile * MT] < 0) return;
    const int tch = blockIdx.y, nch = blockIdx.z;
    const int tid = threadIdx.x, lane = tid & 63, w = tid >> 6;
    const int e = slot_e[tile * MT];
    __shared__ unsigned short Abuf[32768];
    const unsigned short* Asrc = h0seq + ((size_t)(tile * tcount + tch * 8)) * 4096;
    #pragma unroll
    for (int i = 0; i < 16; i++) {
        int o = (i * 256 + tid) * 8;
        *(bf16x8*)&Abuf[o] = *(const bf16x8*)&Asrc[o];
    }
    __syncthreads();
    const unsigned short* Bp = WG + ((size_t)(e * 64 + nch * 16 + w * 4)) * 4096 + lane * 8;
    f32x4 acc[8][4];
    #pragma unroll
    for (int mf = 0; mf < 8; mf++)
        #pragma unroll
        for (int nfi = 0; nfi < 4; nfi++) acc[mf][nfi] = (f32x4){0.f, 0.f, 0.f, 0.f};
    #pragma unroll
    for (int kb = 0; kb < 8; kb++) {
        bf16x8 b0 = *(const bf16x8*)(Bp + 0 * 4096 + kb * 512);
        bf16x8 b1 = *(const bf16x8*)(Bp + 1 * 4096 + kb * 512);
        bf16x8 b2 = *(const bf16x8*)(Bp + 2 * 4096 + kb * 512);
        bf16x8 b3 = *(const bf16x8*)(Bp + 3 * 4096 + kb * 512);
        #pragma unroll
        for (int mf = 0; mf < 8; mf++) {
            bf16x8 a = *(const bf16x8*)&Abuf[(mf * 8 + kb) * 512 + lane * 8];
            acc[mf][0] = __builtin_amdgcn_mfma_f32_16x16x32_bf16(a, b0, acc[mf][0], 0, 0, 0);
            acc[mf][1] = __builtin_amdgcn_mfma_f32_16x16x32_bf16(a, b1, acc[mf][1], 0, 0, 0);
            acc[mf][2] = __builtin_amdgcn_mfma_f32_16x16x32_bf16(a, b2, acc[mf][2], 0, 0, 0);
            acc[mf][3] = __builtin_amdgcn_mfma_f32_16x16x32_bf16(a, b3, acc[mf][3], 0, 0, 0);
        }
    }
    const int l15 = lane & 15;
    #pragma unroll
    for (int mf = 0; mf < 8; mf++) {
        unsigned short* ob = zin1 + ((size_t)(tile * tcount + tch * 8 + mf)) * 16384;
        #pragma unroll
        for (int nfi = 0; nfi < 4; nfi++) {
            int gf = nch * 16 + w * 4 + nfi;
            float bs = bsum1[e * FH + gf * 16 + l15];
            ushort4 v;
            v.x = f2bf(acc[mf][nfi][0] + bs);
            v.y = f2bf(acc[mf][nfi][1] + bs);
            v.z = f2bf(acc[mf][nfi][2] + bs);
            v.w = f2bf(acc[mf][nfi][3] + bs);
            *(ushort4*)(ob + (size_t)(gf * 64 + lane) * 4) = v;
        }
    }
}

// ---------------- fc per slot, weighted ----------------
__global__ __launch_bounds__(256)
void fc_kernel(const float* __restrict__ fcw, const float* __restrict__ fcb,
               const float* __restrict__ h1f,
               const int* __restrict__ slot_b, const int* __restrict__ slot_k,
               const float* __restrict__ slot_w, const int* __restrict__ slot_e,
               float* __restrict__ wout)
{
    int s = blockIdx.x;
    int b = slot_b[s];
    if (b < 0) return;
    int tid = threadIdx.x;
    __shared__ float hv[HH];
    if (tid < HH) hv[tid] = h1f[(size_t)s * HH + tid];
    __syncthreads();
    int e = slot_e[s], kk = slot_k[s];
    float w = slot_w[s];
    for (int v = tid; v < VV; v += 256) {
        float sacc = fcb[e * VV + v];
        const float* fr = fcw + ((size_t)e * VV + v) * HH;
        #pragma unroll 4
        for (int d = 0; d < HH; d++) sacc += hv[d] * fr[d];
        wout[((size_t)b * 2 + kk) * VV + v] = w * sacc;
    }
}

__global__ void combine_kernel(const float* __restrict__ wout, float* __restrict__ out)
{
    int i = blockIdx.x * blockDim.x + threadIdx.x;
    if (i < BB * VV) {
        int b = i / VV, v = i % VV;
        out[i] = wout[((size_t)b * 2) * VV + v] + wout[((size_t)b * 2 + 1) * VV + v];
    }
}

extern "C" void kernel_launch(void* const* d_in, const int* in_sizes, int n_in,
                              void* d_out, int out_size, void* d_ws, size_t ws_size,
                              hipStream_t stream)
{
    const int*   x    = (const int*)d_in[0];
    const float* emb  = (const float*)d_in[1];
    const float* Wih0 = (const float*)d_in[2];
    const float* Whh0 = (const float*)d_in[3];
    const float* bih0 = (const float*)d_in[4];
    const float* bhh0 = (const float*)d_in[5];
    const float* Wih1 = (const float*)d_in[6];
    const float* Whh1 = (const float*)d_in[7];
    const float* bih1 = (const float*)d_in[8];
    const float* bhh1 = (const float*)d_in[9];
    const float* fcw  = (const float*)d_in[10];
    const float* fcb  = (const float*)d_in[11];
    const float* gw1  = (const float*)d_in[12];
    const float* gb1  = (const float*)d_in[13];
    const float* b1g  = (const float*)d_in[14];
    const float* b1b  = (const float*)d_in[15];
    const float* b1m  = (const float*)d_in[16];
    const float* b1v  = (const float*)d_in[17];
    const float* gw2  = (const float*)d_in[18];
    const float* gb2  = (const float*)d_in[19];
    const float* b2g  = (const float*)d_in[20];
    const float* b2b  = (const float*)d_in[21];
    const float* b2m  = (const float*)d_in[22];
    const float* b2v  = (const float*)d_in[23];
    const float* gw3  = (const float*)d_in[24];
    const float* gb3  = (const float*)d_in[25];

    const size_t NWsh = 262144 * 8;   // ushorts per packed weight array

    char* base = (char*)d_ws;
    size_t o = 0;
    auto alloc = [&](size_t bytes) { char* p = base + o; o = (o + bytes + 255) & ~(size_t)255; return p; };

    unsigned short* WR0  = (unsigned short*)alloc(NWsh * 2);
    unsigned short* WR1  = (unsigned short*)alloc(NWsh * 2);
    unsigned short* WG   = (unsigned short*)alloc(NWsh * 2);
    unsigned short* embT = (unsigned short*)alloc((size_t)EE * VV * FH * 2);
    float* bsum1 = (float*)alloc((size_t)EE * FH * 4);
    float* h1f   = (float*)alloc((size_t)SLOTS * HH * 4);
    float* wout  = (float*)alloc((size_t)BB * 2 * VV * 4);
    float* cst0  = (float*)alloc((size_t)NT * 2 * 512 * 4 * 4);
    float* cst1  = (float*)alloc((size_t)NT * 2 * 512 * 4 * 4);
    unsigned short* hsv0 = (unsigned short*)alloc((size_t)NT * 4096 * 2);
    unsigned short* hsv1 = (unsigned short*)alloc((size_t)NT * 4096 * 2);
    unsigned int* hx = (unsigned int*)alloc((size_t)NT * 2 * 2 * 4 * 64 * 4 * 4);
    int* flags = (int*)alloc((size_t)2 * NT * 2 * 4);   // fl0 | fl1
    int* fl0 = flags;
    int* fl1 = flags + NT * 2;
    float* route_w = (float*)alloc((size_t)BB * 2 * 4);
    float* slot_w  = (float*)alloc((size_t)SLOTS * 4);
    int* route_i = (int*)alloc((size_t)BB * 2 * 4);
    int* slot_b  = (int*)alloc((size_t)SLOTS * 4);
    int* slot_k  = (int*)alloc((size_t)SLOTS * 4);
    int* slot_e  = (int*)alloc((size_t)SLOTS * 4);

    const size_t fixed_b = o;
    const size_t per_cc = (size_t)NT * 4096 * 2 + (size_t)NT * 16384 * 2;  // h0seq + zin1 per timestep
    int CC = 8;
    if (ws_size >= fixed_b + 80 * per_cc + 1024) CC = 80;
    else if (ws_size >= fixed_b + 40 * per_cc + 1024) CC = 40;
    else if (ws_size >= fixed_b + 16 * per_cc + 1024) CC = 16;

    unsigned short* h0seq = (unsigned short*)alloc((size_t)NT * CC * 4096 * 2);
    unsigned short* zin1  = (unsigned short*)alloc((size_t)NT * CC * 16384 * 2);

    hipMemsetAsync(flags, 0, (size_t)2 * NT * 2 * 4, stream);

    prep_kernel<<<3104, 256, 0, stream>>>(Whh0, Wih1, Whh1, bih1, bhh1, WR0, WR1, WG, bsum1);
    embw_kernel<<<dim3(EE, 4), 256, 0, stream>>>(emb, Wih0, bih0, bhh0, embT);
    gating_kernel<<<BB, 128, 0, stream>>>(x, emb, gw1, gb1, b1g, b1b, b1m, b1v,
                                          gw2, gb2, b2g, b2b, b2m, b2v, gw3, gb3,
                                          route_i, route_w);
    route_kernel<<<1, 1024, 0, stream>>>(route_i, route_w, slot_b, slot_k, slot_w, slot_e);

    const int nchunks = TT / CC;
    for (int ch = 0; ch < nchunks; ch++) {
        int t0 = ch * CC;
        lstm_kernel<0><<<NT * 2, 512, 0, stream>>>(t0, CC, WR0, embT, zin1, x,
                                                   slot_b, slot_e, h0seq, h1f, cst0, hsv0,
                                                   hx, fl0);
        gemm_zin<<<dim3(NT, CC / 8, 4), 256, 0, stream>>>(CC, h0seq, WG, bsum1,
                                                          slot_b, slot_e, zin1);
        lstm_kernel<1><<<NT * 2, 512, 0, stream>>>(t0, CC, WR1, embT, zin1, x,
                                                   slot_b, slot_e, h0seq, h1f, cst1, hsv1,
                                                   hx, fl1);
    }

    fc_kernel<<<SLOTS, 256, 0, stream>>>(fcw, fcb, h1f, slot_b, slot_k, slot_w, slot_e, wout);
    combine_kernel<<<(BB * VV + 255) / 256, 256, 0, stream>>>(wout, (float*)d_out);
}